// Round 4
// baseline (555.694 us; speedup 1.0000x reference)
//
#include <hip/hip_runtime.h>
#include <hip/hip_bf16.h>

// Problem constants (fixed by reference)
#define NCELLS 16384
#define DIM    768
#define NHEADS 8
#define DHEAD  96           // 768/8
#define MAXH   8
#define ND     (NCELLS * DIM)          // 12582912

// ALL float tensors are fp32 (reference uses jnp.float32 throughout).
// Internal GEMM compute: convert fp32 -> bf16 at staging, MFMA bf16, fp32 out.

using bf16 = __hip_bfloat16;
typedef short  short8  __attribute__((ext_vector_type(8)));
typedef float  floatx4 __attribute__((ext_vector_type(4)));

__device__ inline short f2b(float f) {
    bf16 h = __float2bfloat16(f);
    unsigned short u; __builtin_memcpy(&u, &h, 2); return (short)u;
}

// load 8 consecutive fp32, convert to 8 bf16
__device__ inline short8 ld8(const float* p) {
    floatx4 a = *reinterpret_cast<const floatx4*>(p);
    floatx4 b = *reinterpret_cast<const floatx4*>(p + 4);
    short8 o;
#pragma unroll
    for (int i = 0; i < 4; ++i) { o[i] = f2b(a[i]); o[i + 4] = f2b(b[i]); }
    return o;
}

// cwp on the fly: ce[row] + re[pr] + co[pc], 8 elems at offset `off`, as bf16
__device__ inline short8 cwp8(const float* ce, const float* re, const float* co,
                              int row, int pr, int pc, int off) {
    floatx4 a0 = *reinterpret_cast<const floatx4*>(ce + (size_t)row * DIM + off);
    floatx4 a1 = *reinterpret_cast<const floatx4*>(ce + (size_t)row * DIM + off + 4);
    floatx4 b0 = *reinterpret_cast<const floatx4*>(re + (size_t)pr * DIM + off);
    floatx4 b1 = *reinterpret_cast<const floatx4*>(re + (size_t)pr * DIM + off + 4);
    floatx4 c0 = *reinterpret_cast<const floatx4*>(co + (size_t)pc * DIM + off);
    floatx4 c1 = *reinterpret_cast<const floatx4*>(co + (size_t)pc * DIM + off + 4);
    short8 o;
#pragma unroll
    for (int i = 0; i < 4; ++i) {
        o[i]     = f2b(a0[i] + b0[i] + c0[i]);
        o[i + 4] = f2b(a1[i] + b1[i] + c1[i]);
    }
    return o;
}

// ---------------------------------------------------------------------------
// HKV GEMM: C_bf16[M,N] = A_f32[M,K] @ W_f32[N,K]^T + bias. 256 thr, 64x64.
// Verified fragment layouts (learn_hip m89/m91):
//   A-frag: lane holds A[m=lane&15][k=(lane>>4)*8 + j], j=0..7 contiguous
//   B-frag: lane holds B[k=(lane>>4)*8+j][n=lane&15] == W[n=lane&15][k...]
//   C/D   : col = lane&15, row = (lane>>4)*4 + reg
// ---------------------------------------------------------------------------
__global__ __launch_bounds__(256) void gemm_hkv(
    const float* __restrict__ A, int lda,
    const float* __restrict__ W, int ldw,
    const float* __restrict__ bias,
    bf16* __restrict__ C, int ldc, int K)
{
    __shared__ short As[64 * 40];
    __shared__ short Bs[64 * 40];
    const int tid = threadIdx.x, wave = tid >> 6, lane = tid & 63;
    const int m0 = blockIdx.x * 64, n0 = blockIdx.y * 64;
    const int lr = tid >> 2, lc = (tid & 3) * 8;
    const int fr = lane & 15, fk = (lane >> 4) * 8;

    floatx4 acc[4];
#pragma unroll
    for (int i = 0; i < 4; ++i) acc[i] = (floatx4){0.f, 0.f, 0.f, 0.f};

    for (int k0 = 0; k0 < K; k0 += 32) {
        short8 av = ld8(A + (size_t)(m0 + lr) * lda + k0 + lc);
        short8 wv = ld8(W + (size_t)(n0 + lr) * ldw + k0 + lc);
        __syncthreads();
        *reinterpret_cast<short8*>(&As[lr * 40 + lc]) = av;
        *reinterpret_cast<short8*>(&Bs[lr * 40 + lc]) = wv;
        __syncthreads();
        short8 af = *reinterpret_cast<const short8*>(&As[(wave * 16 + fr) * 40 + fk]);
#pragma unroll
        for (int t = 0; t < 4; ++t) {
            short8 bfv = *reinterpret_cast<const short8*>(&Bs[(t * 16 + fr) * 40 + fk]);
            acc[t] = __builtin_amdgcn_mfma_f32_16x16x32_bf16(af, bfv, acc[t], 0, 0, 0);
        }
    }
    const int col_l = lane & 15, row_q = (lane >> 4) * 4;
#pragma unroll
    for (int t = 0; t < 4; ++t) {
        const int col = n0 + t * 16 + col_l;
        const float bv = bias[col];
#pragma unroll
        for (int r = 0; r < 4; ++r) {
            const int row = m0 + wave * 16 + row_q + r;
            C[(size_t)row * ldc + col] = __float2bfloat16(acc[t][r] + bv);
        }
    }
}

// ---------------------------------------------------------------------------
// q GEMM with on-the-fly cwp A-tiles: q = cwp @ Wq^T + bq -> C_f32 [16384,768]
// ---------------------------------------------------------------------------
__global__ __launch_bounds__(256) void gemm_cwp(
    const float* __restrict__ ce, const float* __restrict__ re,
    const float* __restrict__ co, const int* __restrict__ pos,
    const float* __restrict__ W, const float* __restrict__ bias,
    float* __restrict__ C)
{
    __shared__ short As[64 * 40];
    __shared__ short Bs[64 * 40];
    const int tid = threadIdx.x, wave = tid >> 6, lane = tid & 63;
    const int m0 = blockIdx.x * 64, n0 = blockIdx.y * 64;
    const int lr = tid >> 2, lc = (tid & 3) * 8;
    const int fr = lane & 15, fk = (lane >> 4) * 8;

    const int row = m0 + lr;
    int pr = pos[row * 2 + 0]; pr = min(max(pr, 0), 99);
    int pc = pos[row * 2 + 1]; pc = min(max(pc, 0), 99);

    floatx4 acc[4];
#pragma unroll
    for (int i = 0; i < 4; ++i) acc[i] = (floatx4){0.f, 0.f, 0.f, 0.f};

    for (int k0 = 0; k0 < DIM; k0 += 32) {
        short8 av = cwp8(ce, re, co, row, pr, pc, k0 + lc);
        short8 wv = ld8(W + (size_t)(n0 + lr) * DIM + k0 + lc);
        __syncthreads();
        *reinterpret_cast<short8*>(&As[lr * 40 + lc]) = av;
        *reinterpret_cast<short8*>(&Bs[lr * 40 + lc]) = wv;
        __syncthreads();
        short8 af = *reinterpret_cast<const short8*>(&As[(wave * 16 + fr) * 40 + fk]);
#pragma unroll
        for (int t = 0; t < 4; ++t) {
            short8 bfv = *reinterpret_cast<const short8*>(&Bs[(t * 16 + fr) * 40 + fk]);
            acc[t] = __builtin_amdgcn_mfma_f32_16x16x32_bf16(af, bfv, acc[t], 0, 0, 0);
        }
    }
    const int col_l = lane & 15, row_q = (lane >> 4) * 4;
#pragma unroll
    for (int t = 0; t < 4; ++t) {
        const int col = n0 + t * 16 + col_l;
        const float bv = bias[col];
#pragma unroll
        for (int r = 0; r < 4; ++r) {
            const int rw = m0 + wave * 16 + row_q + r;
            C[(size_t)rw * DIM + col] = acc[t][r] + bv;
        }
    }
}

// ---------------------------------------------------------------------------
// Wide GEMM: C[M,768] = A[M,K] @ W[768,K]^T + bias, 1024 thr, tile 64x768,
// gridDim.y == 1 -> each block owns its 64 rows exclusively -> SAFE in-place
// (C may alias A; all global A reads precede the epilogue's C writes).
// fus_mode: k<768 reads on-the-fly cwp, k>=768 reads A2 (att_out).
// ---------------------------------------------------------------------------
__global__ __launch_bounds__(1024, 1) void gemm_wide(
    const float* A, const float* A2,
    const float* __restrict__ ce, const float* __restrict__ re,
    const float* __restrict__ co, const int* __restrict__ pos,
    const float* __restrict__ W, int ldw,
    const float* __restrict__ bias,
    float* C, int K, int fus_mode)
{
    __shared__ short As[64 * 40];     //  5,120 B
    __shared__ short Bs[768 * 40];    // 61,440 B
    const int tid = threadIdx.x, wave = tid >> 6, lane = tid & 63;
    const int m0 = blockIdx.x * 64;
    const int fr = lane & 15, fk = (lane >> 4) * 8;
    const int wm = (wave & 3) * 16;    // row sub-tile within 64
    const int wn = (wave >> 2) * 192;  // col range start

    const int ar = tid >> 2, ak = (tid & 3) * 8;   // A staging (tid<256)
    int pr = 0, pc = 0;
    if (fus_mode && tid < 256) {
        const int row = m0 + ar;
        pr = pos[row * 2 + 0]; pr = min(max(pr, 0), 99);
        pc = pos[row * 2 + 1]; pc = min(max(pc, 0), 99);
    }

    floatx4 acc[12];
#pragma unroll
    for (int i = 0; i < 12; ++i) acc[i] = (floatx4){0.f, 0.f, 0.f, 0.f};

    for (int k0 = 0; k0 < K; k0 += 32) {
        short8 av;
        if (tid < 256) {
            if (!fus_mode) {
                av = ld8(A + (size_t)(m0 + ar) * DIM + k0 + ak);
            } else if (k0 < DIM) {
                av = cwp8(ce, re, co, m0 + ar, pr, pc, k0 + ak);
            } else {
                av = ld8(A2 + (size_t)(m0 + ar) * DIM + (k0 - DIM) + ak);
            }
        }
        short8 bv[3];
#pragma unroll
        for (int i = 0; i < 3; ++i) {
            const int ch = tid + i * 1024;
            const int br = ch >> 2, bk = (ch & 3) * 8;
            bv[i] = ld8(W + (size_t)br * ldw + k0 + bk);
        }
        __syncthreads();
        if (tid < 256)
            *reinterpret_cast<short8*>(&As[ar * 40 + ak]) = av;
#pragma unroll
        for (int i = 0; i < 3; ++i) {
            const int ch = tid + i * 1024;
            const int br = ch >> 2, bk = (ch & 3) * 8;
            *reinterpret_cast<short8*>(&Bs[br * 40 + bk]) = bv[i];
        }
        __syncthreads();
        short8 af = *reinterpret_cast<const short8*>(&As[(wm + fr) * 40 + fk]);
#pragma unroll
        for (int t = 0; t < 12; ++t) {
            short8 bfv = *reinterpret_cast<const short8*>(&Bs[(wn + t * 16 + fr) * 40 + fk]);
            acc[t] = __builtin_amdgcn_mfma_f32_16x16x32_bf16(af, bfv, acc[t], 0, 0, 0);
        }
    }
    const int col_l = lane & 15, row_q = (lane >> 4) * 4;
#pragma unroll
    for (int t = 0; t < 12; ++t) {
        const int col = wn + t * 16 + col_l;
        const float bvv = bias[col];
#pragma unroll
        for (int r = 0; r < 4; ++r) {
            const int row = m0 + wm + row_q + r;
            C[(size_t)row * DIM + col] = acc[t][r] + bvv;
        }
    }
}

// ---------------------------------------------------------------------------
// Per-cell attention, IN-PLACE: io holds q on entry, ctx on exit (fp32).
// HKV is bf16 (ws). Block reads all 768 q values into LDS before writing.
// ---------------------------------------------------------------------------
__global__ __launch_bounds__(256) void attn_kernel(
    float* io, const bf16* __restrict__ HKV, const int* __restrict__ map,
    float* __restrict__ wout)
{
    const int cell = blockIdx.x;
    const int t = threadIdx.x;
    __shared__ float qs[DIM];
    __shared__ float sc[64];
    __shared__ float at[64];
    __shared__ int   ids[MAXH];
    __shared__ float msk[MAXH];

    if (t < MAXH) {
        int id = map[cell * MAXH + t];
        msk[t] = (id >= 0) ? 1.f : 0.f;
        ids[t] = (id >= 0) ? id : 0;
    }
    for (int d = t; d < DIM; d += 256)
        qs[d] = io[(size_t)cell * DIM + d];
    __syncthreads();

    if (t < 64) {
        const int a = t >> 3, j = t & 7;
        const bf16* kp = HKV + (size_t)ids[j] * 1536 + a * DHEAD;
        float s = 0.f;
        for (int d = 0; d < DHEAD; ++d)
            s += qs[a * DHEAD + d] * __bfloat162float(kp[d]);
        s *= 0.10206207261596577f;  // 1/sqrt(96)
        sc[t] = (msk[j] != 0.f) ? s : -1e9f;
    }
    __syncthreads();

    if (t < NHEADS) {
        float m = -3e38f;
        for (int j = 0; j < MAXH; ++j) m = fmaxf(m, sc[t * 8 + j]);
        float e[MAXH]; float sum = 0.f;
        for (int j = 0; j < MAXH; ++j) { e[j] = expf(sc[t * 8 + j] - m); sum += e[j]; }
        const float inv = 1.f / sum;
        for (int j = 0; j < MAXH; ++j)
            at[t * 8 + j] = (msk[j] != 0.f) ? e[j] * inv : 0.f;
    }
    __syncthreads();

    if (t < MAXH) {
        float s = 0.f;
        for (int a = 0; a < NHEADS; ++a) s += at[a * 8 + t];
        wout[(size_t)cell * MAXH + t] = s * 0.125f;
    }

    for (int d = t; d < DIM; d += 256) {
        const int a = d / DHEAD;
        float s = 0.f;
#pragma unroll
        for (int j = 0; j < MAXH; ++j)
            s += at[a * 8 + j] * __bfloat162float(HKV[(size_t)ids[j] * 1536 + DIM + d]);
        io[(size_t)cell * DIM + d] = s;
    }
}

// ---------------------------------------------------------------------------
// LayerNorm + ReLU + has-select, IN-PLACE on io (h -> enriched, fp32).
// ---------------------------------------------------------------------------
__global__ __launch_bounds__(256) void ln_kernel(
    float* io, const int* __restrict__ map,
    const float* __restrict__ ce, const int* __restrict__ pos,
    const float* __restrict__ re, const float* __restrict__ co,
    const float* __restrict__ g, const float* __restrict__ b)
{
    const int cell = blockIdx.x;
    const int t = threadIdx.x;
    __shared__ float rs[256], rq[256];
    __shared__ int hasf;
    if (t == 0) hasf = 0;

    float* hp = io + (size_t)cell * DIM;
    float v[3];
    float s = 0.f, q2 = 0.f;
#pragma unroll
    for (int i = 0; i < 3; ++i) {
        v[i] = hp[t + i * 256];
        s += v[i]; q2 += v[i] * v[i];
    }
    rs[t] = s; rq[t] = q2;
    __syncthreads();
    if (t < MAXH && map[cell * MAXH + t] >= 0) hasf = 1;
    for (int off = 128; off > 0; off >>= 1) {
        if (t < off) { rs[t] += rs[t + off]; rq[t] += rq[t + off]; }
        __syncthreads();
    }
    const float mu  = rs[0] * (1.f / 768.f);
    const float var = rq[0] * (1.f / 768.f) - mu * mu;
    const float inv = rsqrtf(var + 1e-5f);

    if (hasf) {
#pragma unroll
        for (int i = 0; i < 3; ++i) {
            const int d = t + i * 256;
            float val = (v[i] - mu) * inv * g[d] + b[d];
            hp[d] = fmaxf(val, 0.f);
        }
    } else {
        int pr = pos[cell * 2 + 0]; pr = min(max(pr, 0), 99);
        int pc = pos[cell * 2 + 1]; pc = min(max(pc, 0), 99);
#pragma unroll
        for (int i = 0; i < 3; ++i) {
            const int d = t + i * 256;
            hp[d] = ce[(size_t)cell * DIM + d] + re[(size_t)pr * DIM + d]
                  + co[(size_t)pc * DIM + d];
        }
    }
}

// ---------------------------------------------------------------------------
extern "C" void kernel_launch(void* const* d_in, const int* in_sizes, int n_in,
                              void* d_out, int out_size, void* d_ws, size_t ws_size,
                              hipStream_t stream) {
    (void)in_sizes; (void)n_in; (void)out_size; (void)ws_size;

    const float* cell_emb  = (const float*)d_in[0];
    const float* hdr_emb   = (const float*)d_in[1];
    const int*   map       = (const int*)d_in[2];
    const int*   pos       = (const int*)d_in[3];
    const float* in_proj_w = (const float*)d_in[4];   // [2304, 768]
    const float* in_proj_b = (const float*)d_in[5];
    const float* out_w     = (const float*)d_in[6];   // [768, 768]
    const float* out_b     = (const float*)d_in[7];
    const float* row_emb   = (const float*)d_in[8];
    const float* col_emb   = (const float*)d_in[9];
    const float* fus_w     = (const float*)d_in[10];  // [768, 1536]
    const float* fus_b     = (const float*)d_in[11];
    const float* ln_g      = (const float*)d_in[12];
    const float* ln_b      = (const float*)d_in[13];
    float* out = (float*)d_out;

    // Workspace: ONLY HKV [512,1536] bf16 = 1,572,864 bytes.
    // All [N,768] fp32 intermediates chain in-place through d_out[0:ND]:
    //   q (gemm_cwp) -> ctx (attn, per-cell) -> att_out (wide gemm, row-
    //   exclusive blocks) -> h (wide fusion gemm) -> enriched (ln).
    // Weights output at d_out[ND:], untouched by the in-place chain.
    bf16* HKV = (bf16*)d_ws;

    // 1. HKV = headers @ [Wk;Wv]^T + [bk;bv]   (M=512, N=1536, K=768)
    gemm_hkv<<<dim3(8, 24), 256, 0, stream>>>(
        hdr_emb, DIM, in_proj_w + (size_t)DIM * DIM, DIM, in_proj_b + DIM,
        HKV, 1536, DIM);

    // 2. q = cwp(on-the-fly) @ Wq^T + bq -> d_out
    gemm_cwp<<<dim3(NCELLS / 64, DIM / 64), 256, 0, stream>>>(
        cell_emb, row_emb, col_emb, pos, in_proj_w, in_proj_b, out);

    // 3. attention: q -> ctx in place; weights -> d_out tail
    attn_kernel<<<NCELLS, 256, 0, stream>>>(out, HKV, map, out + ND);

    // 4. att_out = ctx @ out_w^T + out_b  (in-place, row-exclusive blocks)
    gemm_wide<<<NCELLS / 64, 1024, 0, stream>>>(
        out, nullptr, nullptr, nullptr, nullptr, nullptr,
        out_w, DIM, out_b, out, DIM, 0);

    // 5. h = [cwp(on-the-fly) | att_out] @ fus_w^T + fus_b  (in-place)
    gemm_wide<<<NCELLS / 64, 1024, 0, stream>>>(
        nullptr, out, cell_emb, row_emb, col_emb, pos,
        fus_w, 1536, fus_b, out, 1536, 1);

    // 6. LayerNorm + ReLU + select (in-place)
    ln_kernel<<<NCELLS, 256, 0, stream>>>(out, map, cell_emb, pos,
                                          row_emb, col_emb, ln_g, ln_b);
}

// Round 5
// 485.177 us; speedup vs baseline: 1.1453x; 1.1453x over previous
//
#include <hip/hip_runtime.h>
#include <hip/hip_bf16.h>

// Problem constants (fixed by reference)
#define NCELLS 16384
#define DIM    768
#define NHEADS 8
#define DHEAD  96           // 768/8
#define MAXH   8
#define ND     (NCELLS * DIM)          // 12582912

// ALL float tensors are fp32 (reference uses jnp.float32 throughout).
// Internal GEMM compute: convert fp32 -> bf16 at staging, MFMA bf16, fp32 out.

using bf16 = __hip_bfloat16;
typedef short  short8  __attribute__((ext_vector_type(8)));
typedef float  floatx4 __attribute__((ext_vector_type(4)));

__device__ inline short f2b(float f) {
    bf16 h = __float2bfloat16(f);
    unsigned short u; __builtin_memcpy(&u, &h, 2); return (short)u;
}

// load 8 consecutive fp32, convert to 8 bf16
__device__ inline short8 ld8(const float* p) {
    floatx4 a = *reinterpret_cast<const floatx4*>(p);
    floatx4 b = *reinterpret_cast<const floatx4*>(p + 4);
    short8 o;
#pragma unroll
    for (int i = 0; i < 4; ++i) { o[i] = f2b(a[i]); o[i + 4] = f2b(b[i]); }
    return o;
}

// cwp on the fly: ce[row] + re[pr] + co[pc], 8 elems at offset `off`, as bf16
__device__ inline short8 cwp8(const float* ce, const float* re, const float* co,
                              int row, int pr, int pc, int off) {
    floatx4 a0 = *reinterpret_cast<const floatx4*>(ce + (size_t)row * DIM + off);
    floatx4 a1 = *reinterpret_cast<const floatx4*>(ce + (size_t)row * DIM + off + 4);
    floatx4 b0 = *reinterpret_cast<const floatx4*>(re + (size_t)pr * DIM + off);
    floatx4 b1 = *reinterpret_cast<const floatx4*>(re + (size_t)pr * DIM + off + 4);
    floatx4 c0 = *reinterpret_cast<const floatx4*>(co + (size_t)pc * DIM + off);
    floatx4 c1 = *reinterpret_cast<const floatx4*>(co + (size_t)pc * DIM + off + 4);
    short8 o;
#pragma unroll
    for (int i = 0; i < 4; ++i) {
        o[i]     = f2b(a0[i] + b0[i] + c0[i]);
        o[i + 4] = f2b(a1[i] + b1[i] + c1[i]);
    }
    return o;
}

// ===========================================================================
// FAST PATH: 128x128-tile MFMA GEMM (m93 structure).
// 256 thr = 4 waves in 2x2; wave computes 64x64 via 4x4 16x16x32 MFMAs.
// AMODE: 0 = A fp32 [M,lda]; 1 = cwp on the fly; 2 = dual (k<768 cwp,
//        k>=768 A2 bf16 [M,768]).  CMODE: 0 = fp32 out, 1 = bf16 out.
// LDS rows padded to 40 shorts (80 B): worst aliasing 2-way (free, m136).
// ===========================================================================
template <int AMODE, int CMODE>
__global__ __launch_bounds__(256) void gemm128(
    const float* A, int lda, const bf16* A2,
    const float* __restrict__ ce, const float* __restrict__ re,
    const float* __restrict__ co, const int* __restrict__ pos,
    const float* __restrict__ W, int ldw,
    const float* __restrict__ bias,
    float* Cf, bf16* Cb, int ldc, int K)
{
    __shared__ short As[128 * 40];   // 10,240 B
    __shared__ short Bs[128 * 40];   // 10,240 B
    const int tid = threadIdx.x, wave = tid >> 6, lane = tid & 63;
    const int m0 = blockIdx.x * 128, n0 = blockIdx.y * 128;
    const int wr = (wave & 1) * 64;     // wave row offset in tile
    const int wc = (wave >> 1) * 64;    // wave col offset in tile
    const int fr = lane & 15, fk = (lane >> 4) * 8;
    const int sr = tid >> 1;            // staging row 0..127
    const int sk = (tid & 1) * 16;      // staging k offset (elems)

    int pr = 0, pc = 0;
    if (AMODE != 0) {
        const int row = m0 + sr;
        pr = pos[row * 2 + 0]; pr = min(max(pr, 0), 99);
        pc = pos[row * 2 + 1]; pc = min(max(pc, 0), 99);
    }

    floatx4 acc[16];
#pragma unroll
    for (int i = 0; i < 16; ++i) acc[i] = (floatx4){0.f, 0.f, 0.f, 0.f};

    for (int k0 = 0; k0 < K; k0 += 32) {
        short8 a_lo, a_hi;
        if (AMODE == 0) {
            a_lo = ld8(A + (size_t)(m0 + sr) * lda + k0 + sk);
            a_hi = ld8(A + (size_t)(m0 + sr) * lda + k0 + sk + 8);
        } else if (AMODE == 1 || k0 < DIM) {
            a_lo = cwp8(ce, re, co, m0 + sr, pr, pc, k0 + sk);
            a_hi = cwp8(ce, re, co, m0 + sr, pr, pc, k0 + sk + 8);
        } else {
            a_lo = *reinterpret_cast<const short8*>(A2 + (size_t)(m0 + sr) * DIM + (k0 - DIM) + sk);
            a_hi = *reinterpret_cast<const short8*>(A2 + (size_t)(m0 + sr) * DIM + (k0 - DIM) + sk + 8);
        }
        short8 b_lo = ld8(W + (size_t)(n0 + sr) * ldw + k0 + sk);
        short8 b_hi = ld8(W + (size_t)(n0 + sr) * ldw + k0 + sk + 8);

        __syncthreads();   // previous iteration's LDS reads complete
        *reinterpret_cast<short8*>(&As[sr * 40 + sk])     = a_lo;
        *reinterpret_cast<short8*>(&As[sr * 40 + sk + 8]) = a_hi;
        *reinterpret_cast<short8*>(&Bs[sr * 40 + sk])     = b_lo;
        *reinterpret_cast<short8*>(&Bs[sr * 40 + sk + 8]) = b_hi;
        __syncthreads();

        short8 af[4], bfv[4];
#pragma unroll
        for (int i = 0; i < 4; ++i) {
            af[i]  = *reinterpret_cast<const short8*>(&As[(wr + i * 16 + fr) * 40 + fk]);
            bfv[i] = *reinterpret_cast<const short8*>(&Bs[(wc + i * 16 + fr) * 40 + fk]);
        }
#pragma unroll
        for (int i = 0; i < 4; ++i)
#pragma unroll
            for (int j = 0; j < 4; ++j)
                acc[i * 4 + j] = __builtin_amdgcn_mfma_f32_16x16x32_bf16(
                    af[i], bfv[j], acc[i * 4 + j], 0, 0, 0);
    }

    const int col_l = lane & 15, row_q = (lane >> 4) * 4;
#pragma unroll
    for (int j = 0; j < 4; ++j) {
        const int col = n0 + wc + j * 16 + col_l;
        const float bv = bias[col];
#pragma unroll
        for (int i = 0; i < 4; ++i) {
#pragma unroll
            for (int r = 0; r < 4; ++r) {
                const int row = m0 + wr + i * 16 + row_q + r;
                const float v = acc[i * 4 + j][r] + bv;
                if (CMODE == 0) Cf[(size_t)row * ldc + col] = v;
                else            Cb[(size_t)row * ldc + col] = __float2bfloat16(v);
            }
        }
    }
}

// ---------------------------------------------------------------------------
// HKV GEMM: C_bf16[M,N] = A_f32[M,K] @ W_f32[N,K]^T + bias. 256 thr, 64x64.
// ---------------------------------------------------------------------------
__global__ __launch_bounds__(256) void gemm_hkv(
    const float* __restrict__ A, int lda,
    const float* __restrict__ W, int ldw,
    const float* __restrict__ bias,
    bf16* __restrict__ C, int ldc, int K)
{
    __shared__ short As[64 * 40];
    __shared__ short Bs[64 * 40];
    const int tid = threadIdx.x, wave = tid >> 6, lane = tid & 63;
    const int m0 = blockIdx.x * 64, n0 = blockIdx.y * 64;
    const int lr = tid >> 2, lc = (tid & 3) * 8;
    const int fr = lane & 15, fk = (lane >> 4) * 8;

    floatx4 acc[4];
#pragma unroll
    for (int i = 0; i < 4; ++i) acc[i] = (floatx4){0.f, 0.f, 0.f, 0.f};

    for (int k0 = 0; k0 < K; k0 += 32) {
        short8 av = ld8(A + (size_t)(m0 + lr) * lda + k0 + lc);
        short8 wv = ld8(W + (size_t)(n0 + lr) * ldw + k0 + lc);
        __syncthreads();
        *reinterpret_cast<short8*>(&As[lr * 40 + lc]) = av;
        *reinterpret_cast<short8*>(&Bs[lr * 40 + lc]) = wv;
        __syncthreads();
        short8 af = *reinterpret_cast<const short8*>(&As[(wave * 16 + fr) * 40 + fk]);
#pragma unroll
        for (int t = 0; t < 4; ++t) {
            short8 bfv = *reinterpret_cast<const short8*>(&Bs[(t * 16 + fr) * 40 + fk]);
            acc[t] = __builtin_amdgcn_mfma_f32_16x16x32_bf16(af, bfv, acc[t], 0, 0, 0);
        }
    }
    const int col_l = lane & 15, row_q = (lane >> 4) * 4;
#pragma unroll
    for (int t = 0; t < 4; ++t) {
        const int col = n0 + t * 16 + col_l;
        const float bv = bias[col];
#pragma unroll
        for (int r = 0; r < 4; ++r) {
            const int row = m0 + wave * 16 + row_q + r;
            C[(size_t)row * ldc + col] = __float2bfloat16(acc[t][r] + bv);
        }
    }
}

// ===========================================================================
// FALLBACK PATH (verified R4 kernels) — used only if ws_size is too small.
// ===========================================================================
__global__ __launch_bounds__(256) void gemm_cwp(
    const float* __restrict__ ce, const float* __restrict__ re,
    const float* __restrict__ co, const int* __restrict__ pos,
    const float* __restrict__ W, const float* __restrict__ bias,
    float* __restrict__ C)
{
    __shared__ short As[64 * 40];
    __shared__ short Bs[64 * 40];
    const int tid = threadIdx.x, wave = tid >> 6, lane = tid & 63;
    const int m0 = blockIdx.x * 64, n0 = blockIdx.y * 64;
    const int lr = tid >> 2, lc = (tid & 3) * 8;
    const int fr = lane & 15, fk = (lane >> 4) * 8;

    const int row = m0 + lr;
    int pr = pos[row * 2 + 0]; pr = min(max(pr, 0), 99);
    int pc = pos[row * 2 + 1]; pc = min(max(pc, 0), 99);

    floatx4 acc[4];
#pragma unroll
    for (int i = 0; i < 4; ++i) acc[i] = (floatx4){0.f, 0.f, 0.f, 0.f};

    for (int k0 = 0; k0 < DIM; k0 += 32) {
        short8 av = cwp8(ce, re, co, row, pr, pc, k0 + lc);
        short8 wv = ld8(W + (size_t)(n0 + lr) * DIM + k0 + lc);
        __syncthreads();
        *reinterpret_cast<short8*>(&As[lr * 40 + lc]) = av;
        *reinterpret_cast<short8*>(&Bs[lr * 40 + lc]) = wv;
        __syncthreads();
        short8 af = *reinterpret_cast<const short8*>(&As[(wave * 16 + fr) * 40 + fk]);
#pragma unroll
        for (int t = 0; t < 4; ++t) {
            short8 bfv = *reinterpret_cast<const short8*>(&Bs[(t * 16 + fr) * 40 + fk]);
            acc[t] = __builtin_amdgcn_mfma_f32_16x16x32_bf16(af, bfv, acc[t], 0, 0, 0);
        }
    }
    const int col_l = lane & 15, row_q = (lane >> 4) * 4;
#pragma unroll
    for (int t = 0; t < 4; ++t) {
        const int col = n0 + t * 16 + col_l;
        const float bv = bias[col];
#pragma unroll
        for (int r = 0; r < 4; ++r) {
            const int rw = m0 + wave * 16 + row_q + r;
            C[(size_t)rw * DIM + col] = acc[t][r] + bv;
        }
    }
}

__global__ __launch_bounds__(1024, 1) void gemm_wide(
    const float* A, const float* A2,
    const float* __restrict__ ce, const float* __restrict__ re,
    const float* __restrict__ co, const int* __restrict__ pos,
    const float* __restrict__ W, int ldw,
    const float* __restrict__ bias,
    float* C, int K, int fus_mode)
{
    __shared__ short As[64 * 40];
    __shared__ short Bs[768 * 40];
    const int tid = threadIdx.x, wave = tid >> 6, lane = tid & 63;
    const int m0 = blockIdx.x * 64;
    const int fr = lane & 15, fk = (lane >> 4) * 8;
    const int wm = (wave & 3) * 16;
    const int wn = (wave >> 2) * 192;

    const int ar = tid >> 2, ak = (tid & 3) * 8;
    int pr = 0, pc = 0;
    if (fus_mode && tid < 256) {
        const int row = m0 + ar;
        pr = pos[row * 2 + 0]; pr = min(max(pr, 0), 99);
        pc = pos[row * 2 + 1]; pc = min(max(pc, 0), 99);
    }

    floatx4 acc[12];
#pragma unroll
    for (int i = 0; i < 12; ++i) acc[i] = (floatx4){0.f, 0.f, 0.f, 0.f};

    for (int k0 = 0; k0 < K; k0 += 32) {
        short8 av;
        if (tid < 256) {
            if (!fus_mode) {
                av = ld8(A + (size_t)(m0 + ar) * DIM + k0 + ak);
            } else if (k0 < DIM) {
                av = cwp8(ce, re, co, m0 + ar, pr, pc, k0 + ak);
            } else {
                av = ld8(A2 + (size_t)(m0 + ar) * DIM + (k0 - DIM) + ak);
            }
        }
        short8 bv[3];
#pragma unroll
        for (int i = 0; i < 3; ++i) {
            const int ch = tid + i * 1024;
            const int br = ch >> 2, bk = (ch & 3) * 8;
            bv[i] = ld8(W + (size_t)br * ldw + k0 + bk);
        }
        __syncthreads();
        if (tid < 256)
            *reinterpret_cast<short8*>(&As[ar * 40 + ak]) = av;
#pragma unroll
        for (int i = 0; i < 3; ++i) {
            const int ch = tid + i * 1024;
            const int br = ch >> 2, bk = (ch & 3) * 8;
            *reinterpret_cast<short8*>(&Bs[br * 40 + bk]) = bv[i];
        }
        __syncthreads();
        short8 af = *reinterpret_cast<const short8*>(&As[(wm + fr) * 40 + fk]);
#pragma unroll
        for (int t = 0; t < 12; ++t) {
            short8 bfv = *reinterpret_cast<const short8*>(&Bs[(wn + t * 16 + fr) * 40 + fk]);
            acc[t] = __builtin_amdgcn_mfma_f32_16x16x32_bf16(af, bfv, acc[t], 0, 0, 0);
        }
    }
    const int col_l = lane & 15, row_q = (lane >> 4) * 4;
#pragma unroll
    for (int t = 0; t < 12; ++t) {
        const int col = wn + t * 16 + col_l;
        const float bvv = bias[col];
#pragma unroll
        for (int r = 0; r < 4; ++r) {
            const int row = m0 + wm + row_q + r;
            C[(size_t)row * DIM + col] = acc[t][r] + bvv;
        }
    }
}

// ---------------------------------------------------------------------------
// Per-cell attention, IN-PLACE: io holds q on entry, ctx on exit (fp32).
// ---------------------------------------------------------------------------
__global__ __launch_bounds__(256) void attn_kernel(
    float* io, const bf16* __restrict__ HKV, const int* __restrict__ map,
    float* __restrict__ wout)
{
    const int cell = blockIdx.x;
    const int t = threadIdx.x;
    __shared__ float qs[DIM];
    __shared__ float sc[64];
    __shared__ float at[64];
    __shared__ int   ids[MAXH];
    __shared__ float msk[MAXH];

    if (t < MAXH) {
        int id = map[cell * MAXH + t];
        msk[t] = (id >= 0) ? 1.f : 0.f;
        ids[t] = (id >= 0) ? id : 0;
    }
    for (int d = t; d < DIM; d += 256)
        qs[d] = io[(size_t)cell * DIM + d];
    __syncthreads();

    if (t < 64) {
        const int a = t >> 3, j = t & 7;
        const bf16* kp = HKV + (size_t)ids[j] * 1536 + a * DHEAD;
        float s = 0.f;
        for (int d = 0; d < DHEAD; ++d)
            s += qs[a * DHEAD + d] * __bfloat162float(kp[d]);
        s *= 0.10206207261596577f;  // 1/sqrt(96)
        sc[t] = (msk[j] != 0.f) ? s : -1e9f;
    }
    __syncthreads();

    if (t < NHEADS) {
        float m = -3e38f;
        for (int j = 0; j < MAXH; ++j) m = fmaxf(m, sc[t * 8 + j]);
        float e[MAXH]; float sum = 0.f;
        for (int j = 0; j < MAXH; ++j) { e[j] = expf(sc[t * 8 + j] - m); sum += e[j]; }
        const float inv = 1.f / sum;
        for (int j = 0; j < MAXH; ++j)
            at[t * 8 + j] = (msk[j] != 0.f) ? e[j] * inv : 0.f;
    }
    __syncthreads();

    if (t < MAXH) {
        float s = 0.f;
        for (int a = 0; a < NHEADS; ++a) s += at[a * 8 + t];
        wout[(size_t)cell * MAXH + t] = s * 0.125f;
    }

    for (int d = t; d < DIM; d += 256) {
        const int a = d / DHEAD;
        float s = 0.f;
#pragma unroll
        for (int j = 0; j < MAXH; ++j)
            s += at[a * 8 + j] * __bfloat162float(HKV[(size_t)ids[j] * 1536 + DIM + d]);
        io[(size_t)cell * DIM + d] = s;
    }
}

// ---------------------------------------------------------------------------
// LayerNorm + ReLU + has-select, IN-PLACE on io (h -> enriched, fp32).
// ---------------------------------------------------------------------------
__global__ __launch_bounds__(256) void ln_kernel(
    float* io, const int* __restrict__ map,
    const float* __restrict__ ce, const int* __restrict__ pos,
    const float* __restrict__ re, const float* __restrict__ co,
    const float* __restrict__ g, const float* __restrict__ b)
{
    const int cell = blockIdx.x;
    const int t = threadIdx.x;
    __shared__ float rs[256], rq[256];
    __shared__ int hasf;
    if (t == 0) hasf = 0;

    float* hp = io + (size_t)cell * DIM;
    float v[3];
    float s = 0.f, q2 = 0.f;
#pragma unroll
    for (int i = 0; i < 3; ++i) {
        v[i] = hp[t + i * 256];
        s += v[i]; q2 += v[i] * v[i];
    }
    rs[t] = s; rq[t] = q2;
    __syncthreads();
    if (t < MAXH && map[cell * MAXH + t] >= 0) hasf = 1;
    for (int off = 128; off > 0; off >>= 1) {
        if (t < off) { rs[t] += rs[t + off]; rq[t] += rq[t + off]; }
        __syncthreads();
    }
    const float mu  = rs[0] * (1.f / 768.f);
    const float var = rq[0] * (1.f / 768.f) - mu * mu;
    const float inv = rsqrtf(var + 1e-5f);

    if (hasf) {
#pragma unroll
        for (int i = 0; i < 3; ++i) {
            const int d = t + i * 256;
            float val = (v[i] - mu) * inv * g[d] + b[d];
            hp[d] = fmaxf(val, 0.f);
        }
    } else {
        int pr = pos[cell * 2 + 0]; pr = min(max(pr, 0), 99);
        int pc = pos[cell * 2 + 1]; pc = min(max(pc, 0), 99);
#pragma unroll
        for (int i = 0; i < 3; ++i) {
            const int d = t + i * 256;
            hp[d] = ce[(size_t)cell * DIM + d] + re[(size_t)pr * DIM + d]
                  + co[(size_t)pc * DIM + d];
        }
    }
}

// ---------------------------------------------------------------------------
extern "C" void kernel_launch(void* const* d_in, const int* in_sizes, int n_in,
                              void* d_out, int out_size, void* d_ws, size_t ws_size,
                              hipStream_t stream) {
    (void)in_sizes; (void)n_in; (void)out_size;

    const float* cell_emb  = (const float*)d_in[0];
    const float* hdr_emb   = (const float*)d_in[1];
    const int*   map       = (const int*)d_in[2];
    const int*   pos       = (const int*)d_in[3];
    const float* in_proj_w = (const float*)d_in[4];   // [2304, 768]
    const float* in_proj_b = (const float*)d_in[5];
    const float* out_w     = (const float*)d_in[6];   // [768, 768]
    const float* out_b     = (const float*)d_in[7];
    const float* row_emb   = (const float*)d_in[8];
    const float* col_emb   = (const float*)d_in[9];
    const float* fus_w     = (const float*)d_in[10];  // [768, 1536]
    const float* fus_b     = (const float*)d_in[11];
    const float* ln_g      = (const float*)d_in[12];
    const float* ln_b      = (const float*)d_in[13];
    float* out = (float*)d_out;

    // ws: HKV bf16 [512,1536] @ 0 (1,572,864 B); fast path adds
    // att_out bf16 [16384,768] @ 1572864 (25,165,824 B) -> total 26,738,688 B.
    bf16* HKV = (bf16*)d_ws;
    bf16* att_bf = (bf16*)((char*)d_ws + 1572864);
    const bool fast = ws_size >= 26738688;

    // 1. HKV = headers @ [Wk;Wv]^T + [bk;bv]
    gemm_hkv<<<dim3(8, 24), 256, 0, stream>>>(
        hdr_emb, DIM, in_proj_w + (size_t)DIM * DIM, DIM, in_proj_b + DIM,
        HKV, 1536, DIM);

    if (fast) {
        // 2. q = cwp(on-the-fly) @ Wq^T + bq -> d_out (fp32)
        gemm128<1, 0><<<dim3(NCELLS / 128, DIM / 128), 256, 0, stream>>>(
            nullptr, 0, nullptr, cell_emb, row_emb, col_emb, pos,
            in_proj_w, DIM, in_proj_b, out, nullptr, DIM, DIM);

        // 3. attention: q -> ctx in place; weights -> d_out tail
        attn_kernel<<<NCELLS, 256, 0, stream>>>(out, HKV, map, out + ND);

        // 4. att_out = ctx @ out_w^T + out_b -> ws (bf16)
        gemm128<0, 1><<<dim3(NCELLS / 128, DIM / 128), 256, 0, stream>>>(
            out, DIM, nullptr, nullptr, nullptr, nullptr, nullptr,
            out_w, DIM, out_b, nullptr, att_bf, DIM, DIM);

        // 5. h = [cwp(on-the-fly) | att_out] @ fus_w^T + fus_b -> d_out (fp32)
        //    (reads only inputs + ws; ctx in d_out is dead -> no alias hazard)
        gemm128<2, 0><<<dim3(NCELLS / 128, DIM / 128), 256, 0, stream>>>(
            nullptr, 0, att_bf, cell_emb, row_emb, col_emb, pos,
            fus_w, 1536, fus_b, out, nullptr, DIM, 1536);
    } else {
        // Fallback (verified R4 path, ws need = 1.5 MB)
        gemm_cwp<<<dim3(NCELLS / 64, DIM / 64), 256, 0, stream>>>(
            cell_emb, row_emb, col_emb, pos, in_proj_w, in_proj_b, out);
        attn_kernel<<<NCELLS, 256, 0, stream>>>(out, HKV, map, out + ND);
        gemm_wide<<<NCELLS / 64, 1024, 0, stream>>>(
            out, nullptr, nullptr, nullptr, nullptr, nullptr,
            out_w, DIM, out_b, out, DIM, 0);
        gemm_wide<<<NCELLS / 64, 1024, 0, stream>>>(
            nullptr, out, cell_emb, row_emb, col_emb, pos,
            fus_w, 1536, fus_b, out, 1536, 1);
    }

    // 6. LayerNorm + ReLU + select (in-place)
    ln_kernel<<<NCELLS, 256, 0, stream>>>(out, map, cell_emb, pos,
                                          row_emb, col_emb, ln_g, ln_b);
}

// Round 6
// 353.433 us; speedup vs baseline: 1.5723x; 1.3728x over previous
//
#include <hip/hip_runtime.h>
#include <hip/hip_bf16.h>

// Problem constants (fixed by reference)
#define NCELLS 16384
#define DIM    768
#define NHEADS 8
#define DHEAD  96           // 768/8
#define MAXH   8
#define ND     (NCELLS * DIM)          // 12582912

// ALL float tensors are fp32 I/O (reference uses jnp.float32 throughout).
// Internal compute: bf16 operands + MFMA, fp32 accumulate/output.

using bf16 = __hip_bfloat16;
typedef short  short8  __attribute__((ext_vector_type(8)));
typedef short  short4v __attribute__((ext_vector_type(4)));
typedef float  floatx4 __attribute__((ext_vector_type(4)));

__device__ inline short f2b(float f) {
    bf16 h = __float2bfloat16(f);
    unsigned short u; __builtin_memcpy(&u, &h, 2); return (short)u;
}

// load 8 consecutive fp32, convert to 8 bf16
__device__ inline short8 ld8(const float* p) {
    floatx4 a = *reinterpret_cast<const floatx4*>(p);
    floatx4 b = *reinterpret_cast<const floatx4*>(p + 4);
    short8 o;
#pragma unroll
    for (int i = 0; i < 4; ++i) { o[i] = f2b(a[i]); o[i + 4] = f2b(b[i]); }
    return o;
}

// cwp on the fly: ce[row] + re[pr] + co[pc], 8 elems at offset `off`, as bf16
__device__ inline short8 cwp8(const float* ce, const float* re, const float* co,
                              int row, int pr, int pc, int off) {
    floatx4 a0 = *reinterpret_cast<const floatx4*>(ce + (size_t)row * DIM + off);
    floatx4 a1 = *reinterpret_cast<const floatx4*>(ce + (size_t)row * DIM + off + 4);
    floatx4 b0 = *reinterpret_cast<const floatx4*>(re + (size_t)pr * DIM + off);
    floatx4 b1 = *reinterpret_cast<const floatx4*>(re + (size_t)pr * DIM + off + 4);
    floatx4 c0 = *reinterpret_cast<const floatx4*>(co + (size_t)pc * DIM + off);
    floatx4 c1 = *reinterpret_cast<const floatx4*>(co + (size_t)pc * DIM + off + 4);
    short8 o;
#pragma unroll
    for (int i = 0; i < 4; ++i) {
        o[i]     = f2b(a0[i] + b0[i] + c0[i]);
        o[i + 4] = f2b(a1[i] + b1[i] + c1[i]);
    }
    return o;
}

// ===========================================================================
// NEW: pure-bf16 GEMM, 128x128 tile, BK=64, 256 thr (4 waves, 2x2).
// C[M,768] = A[M,K](bf16) @ W[768,K](bf16)^T + bias(f32).
// M = 16384 fixed (128 M-blocks); grid.x = 128*6 linear, XCD-swizzled:
//   mb = id & 127, nb = id >> 7  ->  all 6 nb of one mb share id%8 (same XCD)
//   so the A panel is pulled into one XCD's L2 once.
// DUAL=1: A spans K=1536 as [A | A2] (each [M,768]).
// COUT: 0 = fp32 C, 1 = bf16 C.
// LDS rows padded to 72 shorts: ds_read 2-way bank aliasing only (free, m136).
// ===========================================================================
template <int DUAL, int COUT>
__global__ __launch_bounds__(256) void gemm_bf(
    const bf16* __restrict__ A, const bf16* __restrict__ A2,
    const bf16* __restrict__ W, int ldw,
    const float* __restrict__ bias,
    float* __restrict__ Cf, bf16* __restrict__ Cb, int K)
{
    __shared__ short As[128 * 72];   // 18,432 B
    __shared__ short Bs[128 * 72];   // 18,432 B
    const int tid = threadIdx.x, wave = tid >> 6, lane = tid & 63;
    const int id = blockIdx.x;
    const int m0 = (id & 127) * 128;
    const int n0 = (id >> 7) * 128;
    const int wr = (wave & 1) * 64, wc = (wave >> 1) * 64;
    const int fr = lane & 15, g = lane >> 4;        // fragment row / k-group
    const int sr = tid >> 3, sc = (tid & 7) * 8;    // staging: 32 rows/iter

    floatx4 acc[16];
#pragma unroll
    for (int i = 0; i < 16; ++i) acc[i] = (floatx4){0.f, 0.f, 0.f, 0.f};

    for (int k0 = 0; k0 < K; k0 += 64) {
        // ---- stage A,B tiles: 128 rows x 64 cols bf16 each ----
        const bf16* Ak; int ka;
        if (!DUAL || k0 < DIM) { Ak = A;  ka = k0; }
        else                   { Ak = A2; ka = k0 - DIM; }
        short8 rA[4], rB[4];
#pragma unroll
        for (int i = 0; i < 4; ++i) {
            const int r = i * 32 + sr;
            rA[i] = *reinterpret_cast<const short8*>(Ak + (size_t)(m0 + r) * DIM + ka + sc);
            rB[i] = *reinterpret_cast<const short8*>(W  + (size_t)(n0 + r) * ldw + k0 + sc);
        }
        __syncthreads();   // previous iteration's LDS reads complete
#pragma unroll
        for (int i = 0; i < 4; ++i) {
            const int r = i * 32 + sr;
            *reinterpret_cast<short8*>(&As[r * 72 + sc]) = rA[i];
            *reinterpret_cast<short8*>(&Bs[r * 72 + sc]) = rB[i];
        }
        __syncthreads();

        // ---- 2 x (8 ds_read_b128 + 16 MFMA) ----
#pragma unroll
        for (int kk = 0; kk < 2; ++kk) {
            short8 af[4], bfv[4];
#pragma unroll
            for (int i = 0; i < 4; ++i) {
                af[i]  = *reinterpret_cast<const short8*>(&As[(wr + i * 16 + fr) * 72 + kk * 32 + g * 8]);
                bfv[i] = *reinterpret_cast<const short8*>(&Bs[(wc + i * 16 + fr) * 72 + kk * 32 + g * 8]);
            }
#pragma unroll
            for (int i = 0; i < 4; ++i)
#pragma unroll
                for (int j = 0; j < 4; ++j)
                    acc[i * 4 + j] = __builtin_amdgcn_mfma_f32_16x16x32_bf16(
                        af[i], bfv[j], acc[i * 4 + j], 0, 0, 0);
        }
    }

    const int col_l = lane & 15, row_q = g * 4;
#pragma unroll
    for (int j = 0; j < 4; ++j) {
        const int col = n0 + wc + j * 16 + col_l;
        const float bv = bias[col];
#pragma unroll
        for (int i = 0; i < 4; ++i) {
#pragma unroll
            for (int r = 0; r < 4; ++r) {
                const int row = m0 + wr + i * 16 + row_q + r;
                const float v = acc[i * 4 + j][r] + bv;
                if (COUT == 0) Cf[(size_t)row * DIM + col] = v;
                else           Cb[(size_t)row * DIM + col] = __float2bfloat16(v);
            }
        }
    }
}

// ---------------------------------------------------------------------------
// cwp_b = bf16(ce + re[pr] + co[pc])  [N,768]
// ---------------------------------------------------------------------------
__global__ __launch_bounds__(256) void cwp_b_kernel(
    const float* __restrict__ ce, const int* __restrict__ pos,
    const float* __restrict__ re, const float* __restrict__ co,
    bf16* __restrict__ dst)
{
    const int cell = blockIdx.x;
    int pr = pos[cell * 2 + 0]; pr = min(max(pr, 0), 99);
    int pc = pos[cell * 2 + 1]; pc = min(max(pc, 0), 99);
    const float* a = ce + (size_t)cell * DIM;
    const float* b = re + (size_t)pr * DIM;
    const float* c = co + (size_t)pc * DIM;
    bf16* o = dst + (size_t)cell * DIM;
#pragma unroll
    for (int i = 0; i < 3; ++i) {
        const int d = threadIdx.x + i * 256;
        o[d] = __float2bfloat16(a[d] + b[d] + c[d]);
    }
}

// ---------------------------------------------------------------------------
// fp32 -> bf16 elementwise (weights), vectorized 4-wide. n % 1024 == 0.
// ---------------------------------------------------------------------------
__global__ __launch_bounds__(256) void cvt_kernel(
    const float* __restrict__ src, bf16* __restrict__ dst, int n4)
{
    const int i = blockIdx.x * 256 + threadIdx.x;
    if (i >= n4) return;
    floatx4 v = *reinterpret_cast<const floatx4*>(src + (size_t)i * 4);
    short4v o;
#pragma unroll
    for (int j = 0; j < 4; ++j) o[j] = f2b(v[j]);
    *reinterpret_cast<short4v*>((short*)dst + (size_t)i * 4) = o;
}

// ---------------------------------------------------------------------------
// HKV GEMM: C_bf16[512,1536] = hdr_f32 @ Wkv_f32^T + bias. 256 thr, 64x64.
// ---------------------------------------------------------------------------
__global__ __launch_bounds__(256) void gemm_hkv(
    const float* __restrict__ A, int lda,
    const float* __restrict__ W, int ldw,
    const float* __restrict__ bias,
    bf16* __restrict__ C, int ldc, int K)
{
    __shared__ short As[64 * 40];
    __shared__ short Bs[64 * 40];
    const int tid = threadIdx.x, wave = tid >> 6, lane = tid & 63;
    const int m0 = blockIdx.x * 64, n0 = blockIdx.y * 64;
    const int lr = tid >> 2, lc = (tid & 3) * 8;
    const int fr = lane & 15, fk = (lane >> 4) * 8;

    floatx4 acc[4];
#pragma unroll
    for (int i = 0; i < 4; ++i) acc[i] = (floatx4){0.f, 0.f, 0.f, 0.f};

    for (int k0 = 0; k0 < K; k0 += 32) {
        short8 av = ld8(A + (size_t)(m0 + lr) * lda + k0 + lc);
        short8 wv = ld8(W + (size_t)(n0 + lr) * ldw + k0 + lc);
        __syncthreads();
        *reinterpret_cast<short8*>(&As[lr * 40 + lc]) = av;
        *reinterpret_cast<short8*>(&Bs[lr * 40 + lc]) = wv;
        __syncthreads();
        short8 af = *reinterpret_cast<const short8*>(&As[(wave * 16 + fr) * 40 + fk]);
#pragma unroll
        for (int t = 0; t < 4; ++t) {
            short8 bfv = *reinterpret_cast<const short8*>(&Bs[(t * 16 + fr) * 40 + fk]);
            acc[t] = __builtin_amdgcn_mfma_f32_16x16x32_bf16(af, bfv, acc[t], 0, 0, 0);
        }
    }
    const int col_l = lane & 15, row_q = (lane >> 4) * 4;
#pragma unroll
    for (int t = 0; t < 4; ++t) {
        const int col = n0 + t * 16 + col_l;
        const float bv = bias[col];
#pragma unroll
        for (int r = 0; r < 4; ++r) {
            const int row = m0 + wave * 16 + row_q + r;
            C[(size_t)row * ldc + col] = __float2bfloat16(acc[t][r] + bv);
        }
    }
}

// ---------------------------------------------------------------------------
// Per-cell attention (bf16 q in, bf16 ctx out; separate buffers, no alias).
// ---------------------------------------------------------------------------
__global__ __launch_bounds__(256) void attn_b_kernel(
    const bf16* __restrict__ q, bf16* __restrict__ ctx,
    const bf16* __restrict__ HKV, const int* __restrict__ map,
    float* __restrict__ wout)
{
    const int cell = blockIdx.x;
    const int t = threadIdx.x;
    __shared__ float qs[DIM];
    __shared__ float sc[64];
    __shared__ float at[64];
    __shared__ int   ids[MAXH];
    __shared__ float msk[MAXH];

    if (t < MAXH) {
        int id = map[cell * MAXH + t];
        msk[t] = (id >= 0) ? 1.f : 0.f;
        ids[t] = (id >= 0) ? id : 0;
    }
#pragma unroll
    for (int i = 0; i < 3; ++i) {
        const int d = t + i * 256;
        qs[d] = __bfloat162float(q[(size_t)cell * DIM + d]);
    }
    __syncthreads();

    if (t < 64) {
        const int a = t >> 3, j = t & 7;
        const bf16* kp = HKV + (size_t)ids[j] * 1536 + a * DHEAD;
        float s = 0.f;
        for (int d = 0; d < DHEAD; ++d)
            s += qs[a * DHEAD + d] * __bfloat162float(kp[d]);
        s *= 0.10206207261596577f;  // 1/sqrt(96)
        sc[t] = (msk[j] != 0.f) ? s : -1e9f;
    }
    __syncthreads();

    if (t < NHEADS) {
        float m = -3e38f;
        for (int j = 0; j < MAXH; ++j) m = fmaxf(m, sc[t * 8 + j]);
        float e[MAXH]; float sum = 0.f;
        for (int j = 0; j < MAXH; ++j) { e[j] = expf(sc[t * 8 + j] - m); sum += e[j]; }
        const float inv = 1.f / sum;
        for (int j = 0; j < MAXH; ++j)
            at[t * 8 + j] = (msk[j] != 0.f) ? e[j] * inv : 0.f;
    }
    __syncthreads();

    if (t < MAXH) {
        float s = 0.f;
        for (int a = 0; a < NHEADS; ++a) s += at[a * 8 + t];
        wout[(size_t)cell * MAXH + t] = s * 0.125f;
    }

#pragma unroll
    for (int i = 0; i < 3; ++i) {
        const int d = t + i * 256;
        const int a = d / DHEAD;
        float s = 0.f;
#pragma unroll
        for (int j = 0; j < MAXH; ++j)
            s += at[a * 8 + j] * __bfloat162float(HKV[(size_t)ids[j] * 1536 + DIM + d]);
        ctx[(size_t)cell * DIM + d] = __float2bfloat16(s);
    }
}

// ---------------------------------------------------------------------------
// LayerNorm + ReLU + has-select, IN-PLACE on io (h -> enriched, fp32).
// ---------------------------------------------------------------------------
__global__ __launch_bounds__(256) void ln_kernel(
    float* io, const int* __restrict__ map,
    const float* __restrict__ ce, const int* __restrict__ pos,
    const float* __restrict__ re, const float* __restrict__ co,
    const float* __restrict__ g, const float* __restrict__ b)
{
    const int cell = blockIdx.x;
    const int t = threadIdx.x;
    __shared__ float rs[256], rq[256];
    __shared__ int hasf;
    if (t == 0) hasf = 0;

    float* hp = io + (size_t)cell * DIM;
    float v[3];
    float s = 0.f, q2 = 0.f;
#pragma unroll
    for (int i = 0; i < 3; ++i) {
        v[i] = hp[t + i * 256];
        s += v[i]; q2 += v[i] * v[i];
    }
    rs[t] = s; rq[t] = q2;
    __syncthreads();
    if (t < MAXH && map[cell * MAXH + t] >= 0) hasf = 1;
    for (int off = 128; off > 0; off >>= 1) {
        if (t < off) { rs[t] += rs[t + off]; rq[t] += rq[t + off]; }
        __syncthreads();
    }
    const float mu  = rs[0] * (1.f / 768.f);
    const float var = rq[0] * (1.f / 768.f) - mu * mu;
    const float inv = rsqrtf(var + 1e-5f);

    if (hasf) {
#pragma unroll
        for (int i = 0; i < 3; ++i) {
            const int d = t + i * 256;
            float val = (v[i] - mu) * inv * g[d] + b[d];
            hp[d] = fmaxf(val, 0.f);
        }
    } else {
        int pr = pos[cell * 2 + 0]; pr = min(max(pr, 0), 99);
        int pc = pos[cell * 2 + 1]; pc = min(max(pc, 0), 99);
#pragma unroll
        for (int i = 0; i < 3; ++i) {
            const int d = t + i * 256;
            hp[d] = ce[(size_t)cell * DIM + d] + re[(size_t)pr * DIM + d]
                  + co[(size_t)pc * DIM + d];
        }
    }
}

// ===========================================================================
// FALLBACK (verified R5 fast path) — only used if ws_size < 56.6 MB.
// ===========================================================================
template <int AMODE, int CMODE>
__global__ __launch_bounds__(256) void gemm128(
    const float* A, int lda, const bf16* A2,
    const float* __restrict__ ce, const float* __restrict__ re,
    const float* __restrict__ co, const int* __restrict__ pos,
    const float* __restrict__ W, int ldw,
    const float* __restrict__ bias,
    float* Cf, bf16* Cb, int ldc, int K)
{
    __shared__ short As[128 * 40];
    __shared__ short Bs[128 * 40];
    const int tid = threadIdx.x, wave = tid >> 6, lane = tid & 63;
    const int m0 = blockIdx.x * 128, n0 = blockIdx.y * 128;
    const int wr = (wave & 1) * 64;
    const int wc = (wave >> 1) * 64;
    const int fr = lane & 15, fk = (lane >> 4) * 8;
    const int sr = tid >> 1;
    const int sk = (tid & 1) * 16;

    int pr = 0, pc = 0;
    if (AMODE != 0) {
        const int row = m0 + sr;
        pr = pos[row * 2 + 0]; pr = min(max(pr, 0), 99);
        pc = pos[row * 2 + 1]; pc = min(max(pc, 0), 99);
    }

    floatx4 acc[16];
#pragma unroll
    for (int i = 0; i < 16; ++i) acc[i] = (floatx4){0.f, 0.f, 0.f, 0.f};

    for (int k0 = 0; k0 < K; k0 += 32) {
        short8 a_lo, a_hi;
        if (AMODE == 0) {
            a_lo = ld8(A + (size_t)(m0 + sr) * lda + k0 + sk);
            a_hi = ld8(A + (size_t)(m0 + sr) * lda + k0 + sk + 8);
        } else if (AMODE == 1 || k0 < DIM) {
            a_lo = cwp8(ce, re, co, m0 + sr, pr, pc, k0 + sk);
            a_hi = cwp8(ce, re, co, m0 + sr, pr, pc, k0 + sk + 8);
        } else {
            a_lo = *reinterpret_cast<const short8*>(A2 + (size_t)(m0 + sr) * DIM + (k0 - DIM) + sk);
            a_hi = *reinterpret_cast<const short8*>(A2 + (size_t)(m0 + sr) * DIM + (k0 - DIM) + sk + 8);
        }
        short8 b_lo = ld8(W + (size_t)(n0 + sr) * ldw + k0 + sk);
        short8 b_hi = ld8(W + (size_t)(n0 + sr) * ldw + k0 + sk + 8);

        __syncthreads();
        *reinterpret_cast<short8*>(&As[sr * 40 + sk])     = a_lo;
        *reinterpret_cast<short8*>(&As[sr * 40 + sk + 8]) = a_hi;
        *reinterpret_cast<short8*>(&Bs[sr * 40 + sk])     = b_lo;
        *reinterpret_cast<short8*>(&Bs[sr * 40 + sk + 8]) = b_hi;
        __syncthreads();

        short8 af[4], bfv[4];
#pragma unroll
        for (int i = 0; i < 4; ++i) {
            af[i]  = *reinterpret_cast<const short8*>(&As[(wr + i * 16 + fr) * 40 + fk]);
            bfv[i] = *reinterpret_cast<const short8*>(&Bs[(wc + i * 16 + fr) * 40 + fk]);
        }
#pragma unroll
        for (int i = 0; i < 4; ++i)
#pragma unroll
            for (int j = 0; j < 4; ++j)
                acc[i * 4 + j] = __builtin_amdgcn_mfma_f32_16x16x32_bf16(
                    af[i], bfv[j], acc[i * 4 + j], 0, 0, 0);
    }

    const int col_l = lane & 15, row_q = (lane >> 4) * 4;
#pragma unroll
    for (int j = 0; j < 4; ++j) {
        const int col = n0 + wc + j * 16 + col_l;
        const float bv = bias[col];
#pragma unroll
        for (int i = 0; i < 4; ++i) {
#pragma unroll
            for (int r = 0; r < 4; ++r) {
                const int row = m0 + wr + i * 16 + row_q + r;
                const float v = acc[i * 4 + j][r] + bv;
                if (CMODE == 0) Cf[(size_t)row * ldc + col] = v;
                else            Cb[(size_t)row * ldc + col] = __float2bfloat16(v);
            }
        }
    }
}

__global__ __launch_bounds__(256) void attn_kernel(
    float* io, const bf16* __restrict__ HKV, const int* __restrict__ map,
    float* __restrict__ wout)
{
    const int cell = blockIdx.x;
    const int t = threadIdx.x;
    __shared__ float qs[DIM];
    __shared__ float sc[64];
    __shared__ float at[64];
    __shared__ int   ids[MAXH];
    __shared__ float msk[MAXH];

    if (t < MAXH) {
        int id = map[cell * MAXH + t];
        msk[t] = (id >= 0) ? 1.f : 0.f;
        ids[t] = (id >= 0) ? id : 0;
    }
    for (int d = t; d < DIM; d += 256)
        qs[d] = io[(size_t)cell * DIM + d];
    __syncthreads();

    if (t < 64) {
        const int a = t >> 3, j = t & 7;
        const bf16* kp = HKV + (size_t)ids[j] * 1536 + a * DHEAD;
        float s = 0.f;
        for (int d = 0; d < DHEAD; ++d)
            s += qs[a * DHEAD + d] * __bfloat162float(kp[d]);
        s *= 0.10206207261596577f;
        sc[t] = (msk[j] != 0.f) ? s : -1e9f;
    }
    __syncthreads();

    if (t < NHEADS) {
        float m = -3e38f;
        for (int j = 0; j < MAXH; ++j) m = fmaxf(m, sc[t * 8 + j]);
        float e[MAXH]; float sum = 0.f;
        for (int j = 0; j < MAXH; ++j) { e[j] = expf(sc[t * 8 + j] - m); sum += e[j]; }
        const float inv = 1.f / sum;
        for (int j = 0; j < MAXH; ++j)
            at[t * 8 + j] = (msk[j] != 0.f) ? e[j] * inv : 0.f;
    }
    __syncthreads();

    if (t < MAXH) {
        float s = 0.f;
        for (int a = 0; a < NHEADS; ++a) s += at[a * 8 + t];
        wout[(size_t)cell * MAXH + t] = s * 0.125f;
    }

    for (int d = t; d < DIM; d += 256) {
        const int a = d / DHEAD;
        float s = 0.f;
#pragma unroll
        for (int j = 0; j < MAXH; ++j)
            s += at[a * 8 + j] * __bfloat162float(HKV[(size_t)ids[j] * 1536 + DIM + d]);
        io[(size_t)cell * DIM + d] = s;
    }
}

// ---------------------------------------------------------------------------
extern "C" void kernel_launch(void* const* d_in, const int* in_sizes, int n_in,
                              void* d_out, int out_size, void* d_ws, size_t ws_size,
                              hipStream_t stream) {
    (void)in_sizes; (void)n_in; (void)out_size;

    const float* cell_emb  = (const float*)d_in[0];
    const float* hdr_emb   = (const float*)d_in[1];
    const int*   map       = (const int*)d_in[2];
    const int*   pos       = (const int*)d_in[3];
    const float* in_proj_w = (const float*)d_in[4];   // [2304, 768]
    const float* in_proj_b = (const float*)d_in[5];
    const float* out_w     = (const float*)d_in[6];   // [768, 768]
    const float* out_b     = (const float*)d_in[7];
    const float* row_emb   = (const float*)d_in[8];
    const float* col_emb   = (const float*)d_in[9];
    const float* fus_w     = (const float*)d_in[10];  // [768, 1536]
    const float* fus_b     = (const float*)d_in[11];
    const float* ln_g      = (const float*)d_in[12];
    const float* ln_b      = (const float*)d_in[13];
    float* out = (float*)d_out;

    // ws layout (bytes):
    //   HKV   bf16 [512,1536]  @ 0          ( 1,572,864)
    //   att_b bf16 [16384,768] @ 1572864    (25,165,824)
    //   cwp_b bf16 [16384,768] @ 26738688   (25,165,824)
    //   Wq_b  bf16 [768,768]   @ 51904512   ( 1,179,648)
    //   Wo_b  bf16 [768,768]   @ 53084160   ( 1,179,648)
    //   Wf_b  bf16 [768,1536]  @ 54263808   ( 2,359,296)  -> total 56,623,104
    char* ws = (char*)d_ws;
    bf16* HKV    = (bf16*)ws;
    bf16* att_b  = (bf16*)(ws + 1572864);
    bf16* cwp_b  = (bf16*)(ws + 26738688);
    bf16* Wq_b   = (bf16*)(ws + 51904512);
    bf16* Wo_b   = (bf16*)(ws + 53084160);
    bf16* Wf_b   = (bf16*)(ws + 54263808);
    // d_out raw-byte scratch: q_b bf16 @ [0,25165824), ctx_b @ [25165824,50331648)
    bf16* q_b    = (bf16*)d_out;
    bf16* ctx_b  = (bf16*)((char*)d_out + 25165824);

    // 1. HKV = headers @ [Wk;Wv]^T + [bk;bv]  (fp32 in, bf16 out)
    gemm_hkv<<<dim3(8, 24), 256, 0, stream>>>(
        hdr_emb, DIM, in_proj_w + (size_t)DIM * DIM, DIM, in_proj_b + DIM,
        HKV, 1536, DIM);

    if (ws_size >= 56623104) {
        // 2. one-time bf16 conversions
        cwp_b_kernel<<<NCELLS, 256, 0, stream>>>(cell_emb, pos, row_emb, col_emb, cwp_b);
        cvt_kernel<<<(589824 / 4 + 255) / 256, 256, 0, stream>>>(in_proj_w, Wq_b, 589824 / 4);
        cvt_kernel<<<(589824 / 4 + 255) / 256, 256, 0, stream>>>(out_w, Wo_b, 589824 / 4);
        cvt_kernel<<<(1179648 / 4 + 255) / 256, 256, 0, stream>>>(fus_w, Wf_b, 1179648 / 4);

        // 3. q_b = cwp_b @ Wq_b^T + bq  (bf16 out -> d_out bytes [0,25MB))
        gemm_bf<0, 1><<<768, 256, 0, stream>>>(
            cwp_b, nullptr, Wq_b, DIM, in_proj_b, nullptr, q_b, DIM);

        // 4. attention: q_b -> ctx_b; weights -> d_out tail (fp32)
        attn_b_kernel<<<NCELLS, 256, 0, stream>>>(q_b, ctx_b, HKV, map, out + ND);

        // 5. att_b = ctx_b @ Wo_b^T + out_b  (bf16 out -> ws)
        gemm_bf<0, 1><<<768, 256, 0, stream>>>(
            ctx_b, nullptr, Wo_b, DIM, out_b, nullptr, att_b, DIM);

        // 6. h = [cwp_b | att_b] @ Wf_b^T + fus_b  (fp32 out -> d_out; q_b/ctx_b dead)
        gemm_bf<1, 0><<<768, 256, 0, stream>>>(
            cwp_b, att_b, Wf_b, 1536, fus_b, out, nullptr, 1536);
    } else {
        // Fallback: verified R5 fast path (needs 26,738,688 B of ws)
        bf16* att_bf = (bf16*)(ws + 1572864);
        gemm128<1, 0><<<dim3(NCELLS / 128, DIM / 128), 256, 0, stream>>>(
            nullptr, 0, nullptr, cell_emb, row_emb, col_emb, pos,
            in_proj_w, DIM, in_proj_b, out, nullptr, DIM, DIM);
        attn_kernel<<<NCELLS, 256, 0, stream>>>(out, HKV, map, out + ND);
        gemm128<0, 1><<<dim3(NCELLS / 128, DIM / 128), 256, 0, stream>>>(
            out, DIM, nullptr, nullptr, nullptr, nullptr, nullptr,
            out_w, DIM, out_b, nullptr, att_bf, DIM, DIM);
        gemm128<2, 0><<<dim3(NCELLS / 128, DIM / 128), 256, 0, stream>>>(
            nullptr, 0, att_bf, cell_emb, row_emb, col_emb, pos,
            fus_w, 1536, fus_b, out, nullptr, DIM, 1536);
    }

    // 7. LayerNorm + ReLU + select (in-place on d_out fp32)
    ln_kernel<<<NCELLS, 256, 0, stream>>>(out, map, cell_emb, pos,
                                          row_emb, col_emb, ln_g, ln_b);
}

// Round 7
// 321.796 us; speedup vs baseline: 1.7269x; 1.0983x over previous
//
#include <hip/hip_runtime.h>
#include <hip/hip_bf16.h>

// Problem constants (fixed by reference)
#define NCELLS 16384
#define DIM    768
#define NHEADS 8
#define DHEAD  96           // 768/8
#define MAXH   8
#define ND     (NCELLS * DIM)          // 12582912

// ALL float tensors are fp32 I/O (reference uses jnp.float32 throughout).
// Internal compute: bf16 operands + MFMA, fp32 accumulate/output.

using bf16 = __hip_bfloat16;
typedef short  short8  __attribute__((ext_vector_type(8)));
typedef short  short4v __attribute__((ext_vector_type(4)));
typedef float  floatx4 __attribute__((ext_vector_type(4)));

__device__ inline short f2b(float f) {
    bf16 h = __float2bfloat16(f);
    unsigned short u; __builtin_memcpy(&u, &h, 2); return (short)u;
}

// load 8 consecutive fp32, convert to 8 bf16
__device__ inline short8 ld8(const float* p) {
    floatx4 a = *reinterpret_cast<const floatx4*>(p);
    floatx4 b = *reinterpret_cast<const floatx4*>(p + 4);
    short8 o;
#pragma unroll
    for (int i = 0; i < 4; ++i) { o[i] = f2b(a[i]); o[i + 4] = f2b(b[i]); }
    return o;
}

// cwp on the fly: ce[row] + re[pr] + co[pc], 8 elems at offset `off`, as bf16
__device__ inline short8 cwp8(const float* ce, const float* re, const float* co,
                              int row, int pr, int pc, int off) {
    floatx4 a0 = *reinterpret_cast<const floatx4*>(ce + (size_t)row * DIM + off);
    floatx4 a1 = *reinterpret_cast<const floatx4*>(ce + (size_t)row * DIM + off + 4);
    floatx4 b0 = *reinterpret_cast<const floatx4*>(re + (size_t)pr * DIM + off);
    floatx4 b1 = *reinterpret_cast<const floatx4*>(re + (size_t)pr * DIM + off + 4);
    floatx4 c0 = *reinterpret_cast<const floatx4*>(co + (size_t)pc * DIM + off);
    floatx4 c1 = *reinterpret_cast<const floatx4*>(co + (size_t)pc * DIM + off + 4);
    short8 o;
#pragma unroll
    for (int i = 0; i < 4; ++i) {
        o[i]     = f2b(a0[i] + b0[i] + c0[i]);
        o[i + 4] = f2b(a1[i] + b1[i] + c1[i]);
    }
    return o;
}

// async 16B global -> LDS (direct DMA, no VGPR round-trip). Destination is
// wave-uniform base + lane*16 (m104/m108): pass per-lane addr; lane0 = base.
__device__ __forceinline__ void cp16(const void* g, void* l) {
    __builtin_amdgcn_global_load_lds(
        (const __attribute__((address_space(1))) void*)g,
        (__attribute__((address_space(3))) void*)l, 16, 0, 0);
}

// ===========================================================================
// Pure-bf16 GEMM, 128x128 tile, BK=64, 256 thr (4 waves, 2x2), staging via
// global_load_lds width=16 (m97 ladder rung: 517->874 TF on 4096^3).
// C[M,768] = A[M,K](bf16) @ W[768,K](bf16)^T + bias(f32).
// grid.x = 128*6 linear, XCD-swizzled: mb = id&127, nb = id>>7 -> all 6 nb of
// one mb share id%8 (same XCD) so the A panel lands in one XCD L2 once.
// LDS tiles UNPADDED [128][64] shorts (global_load_lds needs linear dest);
// bank conflicts broken by XOR-swizzling the k-group with row&7 on the
// GLOBAL SOURCE address + matching XOR on the ds_read index. Worst aliasing
// 2-way = free (m136).
// DUAL=1: A spans K=1536 as [A | A2] (each [M,768]). COUT: 0=f32 C, 1=bf16 C.
// ===========================================================================
template <int DUAL, int COUT>
__global__ __launch_bounds__(256) void gemm_bf(
    const bf16* __restrict__ A, const bf16* __restrict__ A2,
    const bf16* __restrict__ W, int ldw,
    const float* __restrict__ bias,
    float* __restrict__ Cf, bf16* __restrict__ Cb, int K)
{
    __shared__ short As[128 * 64];   // 16,384 B
    __shared__ short Bs[128 * 64];   // 16,384 B
    const int tid = threadIdx.x, wave = tid >> 6, lane = tid & 63;
    const int id = blockIdx.x;
    const int m0 = (id & 127) * 128;
    const int n0 = (id >> 7) * 128;
    const int wr = (wave & 1) * 64, wc = (wave >> 1) * 64;
    const int fr = lane & 15, kg = lane >> 4;   // fragment row / k-group

    // staging: 16 chunks of 1024 B per tile; wave handles chunks i*4+wave.
    // lane covers row c*8 + (lane>>3); global k-group XOR-swizzled by row&7.
    const int srow = lane >> 3;            // row within chunk (== row&7)
    const int scol = (lane & 7) ^ srow;    // swizzled source k-group

    floatx4 acc[16];
#pragma unroll
    for (int i = 0; i < 16; ++i) acc[i] = (floatx4){0.f, 0.f, 0.f, 0.f};

    for (int k0 = 0; k0 < K; k0 += 64) {
        const bf16* Ak; int ka;
        if (!DUAL || k0 < DIM) { Ak = A;  ka = k0; }
        else                   { Ak = A2; ka = k0 - DIM; }

        __syncthreads();   // previous iteration's ds_reads complete
#pragma unroll
        for (int i = 0; i < 4; ++i) {
            const int c = i * 4 + wave;
            const int row = c * 8 + srow;
            cp16(Ak + (size_t)(m0 + row) * DIM + ka + scol * 8,
                 &As[c * 512 + lane * 8]);
            cp16(W  + (size_t)(n0 + row) * ldw + k0 + scol * 8,
                 &Bs[c * 512 + lane * 8]);
        }
        __syncthreads();   // vmcnt(0) drained: tiles landed

#pragma unroll
        for (int kk = 0; kk < 2; ++kk) {
            short8 af[4], bfv[4];
#pragma unroll
            for (int i = 0; i < 4; ++i) {
                const int sa = ((kk * 4 + kg) ^ (fr & 7)) * 8;
                af[i]  = *reinterpret_cast<const short8*>(&As[(wr + i * 16 + fr) * 64 + sa]);
                bfv[i] = *reinterpret_cast<const short8*>(&Bs[(wc + i * 16 + fr) * 64 + sa]);
            }
#pragma unroll
            for (int i = 0; i < 4; ++i)
#pragma unroll
                for (int j = 0; j < 4; ++j)
                    acc[i * 4 + j] = __builtin_amdgcn_mfma_f32_16x16x32_bf16(
                        af[i], bfv[j], acc[i * 4 + j], 0, 0, 0);
        }
    }

    const int col_l = lane & 15, row_q = kg * 4;
#pragma unroll
    for (int j = 0; j < 4; ++j) {
        const int col = n0 + wc + j * 16 + col_l;
        const float bv = bias[col];
#pragma unroll
        for (int i = 0; i < 4; ++i) {
#pragma unroll
            for (int r = 0; r < 4; ++r) {
                const int row = m0 + wr + i * 16 + row_q + r;
                const float v = acc[i * 4 + j][r] + bv;
                if (COUT == 0) Cf[(size_t)row * DIM + col] = v;
                else           Cb[(size_t)row * DIM + col] = __float2bfloat16(v);
            }
        }
    }
}

// ---------------------------------------------------------------------------
// cwp_b = bf16(ce + re[pr] + co[pc])  [N,768]
// ---------------------------------------------------------------------------
__global__ __launch_bounds__(256) void cwp_b_kernel(
    const float* __restrict__ ce, const int* __restrict__ pos,
    const float* __restrict__ re, const float* __restrict__ co,
    bf16* __restrict__ dst)
{
    const int cell = blockIdx.x;
    int pr = pos[cell * 2 + 0]; pr = min(max(pr, 0), 99);
    int pc = pos[cell * 2 + 1]; pc = min(max(pc, 0), 99);
    const float* a = ce + (size_t)cell * DIM;
    const float* b = re + (size_t)pr * DIM;
    const float* c = co + (size_t)pc * DIM;
    bf16* o = dst + (size_t)cell * DIM;
#pragma unroll
    for (int i = 0; i < 3; ++i) {
        const int d = threadIdx.x + i * 256;
        o[d] = __float2bfloat16(a[d] + b[d] + c[d]);
    }
}

// ---------------------------------------------------------------------------
// fp32 -> bf16 elementwise (weights), vectorized 4-wide. n % 1024 == 0.
// ---------------------------------------------------------------------------
__global__ __launch_bounds__(256) void cvt_kernel(
    const float* __restrict__ src, bf16* __restrict__ dst, int n4)
{
    const int i = blockIdx.x * 256 + threadIdx.x;
    if (i >= n4) return;
    floatx4 v = *reinterpret_cast<const floatx4*>(src + (size_t)i * 4);
    short4v o;
#pragma unroll
    for (int j = 0; j < 4; ++j) o[j] = f2b(v[j]);
    *reinterpret_cast<short4v*>((short*)dst + (size_t)i * 4) = o;
}

// ---------------------------------------------------------------------------
// HKV GEMM: C_bf16[512,1536] = hdr_f32 @ Wkv_f32^T + bias. 256 thr, 64x64.
// ---------------------------------------------------------------------------
__global__ __launch_bounds__(256) void gemm_hkv(
    const float* __restrict__ A, int lda,
    const float* __restrict__ W, int ldw,
    const float* __restrict__ bias,
    bf16* __restrict__ C, int ldc, int K)
{
    __shared__ short As[64 * 40];
    __shared__ short Bs[64 * 40];
    const int tid = threadIdx.x, wave = tid >> 6, lane = tid & 63;
    const int m0 = blockIdx.x * 64, n0 = blockIdx.y * 64;
    const int lr = tid >> 2, lc = (tid & 3) * 8;
    const int fr = lane & 15, fk = (lane >> 4) * 8;

    floatx4 acc[4];
#pragma unroll
    for (int i = 0; i < 4; ++i) acc[i] = (floatx4){0.f, 0.f, 0.f, 0.f};

    for (int k0 = 0; k0 < K; k0 += 32) {
        short8 av = ld8(A + (size_t)(m0 + lr) * lda + k0 + lc);
        short8 wv = ld8(W + (size_t)(n0 + lr) * ldw + k0 + lc);
        __syncthreads();
        *reinterpret_cast<short8*>(&As[lr * 40 + lc]) = av;
        *reinterpret_cast<short8*>(&Bs[lr * 40 + lc]) = wv;
        __syncthreads();
        short8 af = *reinterpret_cast<const short8*>(&As[(wave * 16 + fr) * 40 + fk]);
#pragma unroll
        for (int t = 0; t < 4; ++t) {
            short8 bfv = *reinterpret_cast<const short8*>(&Bs[(t * 16 + fr) * 40 + fk]);
            acc[t] = __builtin_amdgcn_mfma_f32_16x16x32_bf16(af, bfv, acc[t], 0, 0, 0);
        }
    }
    const int col_l = lane & 15, row_q = (lane >> 4) * 4;
#pragma unroll
    for (int t = 0; t < 4; ++t) {
        const int col = n0 + t * 16 + col_l;
        const float bv = bias[col];
#pragma unroll
        for (int r = 0; r < 4; ++r) {
            const int row = m0 + wave * 16 + row_q + r;
            C[(size_t)row * ldc + col] = __float2bfloat16(acc[t][r] + bv);
        }
    }
}

// ---------------------------------------------------------------------------
// Per-cell attention (bf16 q in, bf16 ctx out; separate buffers, no alias).
// ---------------------------------------------------------------------------
__global__ __launch_bounds__(256) void attn_b_kernel(
    const bf16* __restrict__ q, bf16* __restrict__ ctx,
    const bf16* __restrict__ HKV, const int* __restrict__ map,
    float* __restrict__ wout)
{
    const int cell = blockIdx.x;
    const int t = threadIdx.x;
    __shared__ float qs[DIM];
    __shared__ float sc[64];
    __shared__ float at[64];
    __shared__ int   ids[MAXH];
    __shared__ float msk[MAXH];

    if (t < MAXH) {
        int id = map[cell * MAXH + t];
        msk[t] = (id >= 0) ? 1.f : 0.f;
        ids[t] = (id >= 0) ? id : 0;
    }
#pragma unroll
    for (int i = 0; i < 3; ++i) {
        const int d = t + i * 256;
        qs[d] = __bfloat162float(q[(size_t)cell * DIM + d]);
    }
    __syncthreads();

    if (t < 64) {
        const int a = t >> 3, j = t & 7;
        const bf16* kp = HKV + (size_t)ids[j] * 1536 + a * DHEAD;
        float s = 0.f;
        for (int d = 0; d < DHEAD; ++d)
            s += qs[a * DHEAD + d] * __bfloat162float(kp[d]);
        s *= 0.10206207261596577f;  // 1/sqrt(96)
        sc[t] = (msk[j] != 0.f) ? s : -1e9f;
    }
    __syncthreads();

    if (t < NHEADS) {
        float m = -3e38f;
        for (int j = 0; j < MAXH; ++j) m = fmaxf(m, sc[t * 8 + j]);
        float e[MAXH]; float sum = 0.f;
        for (int j = 0; j < MAXH; ++j) { e[j] = expf(sc[t * 8 + j] - m); sum += e[j]; }
        const float inv = 1.f / sum;
        for (int j = 0; j < MAXH; ++j)
            at[t * 8 + j] = (msk[j] != 0.f) ? e[j] * inv : 0.f;
    }
    __syncthreads();

    if (t < MAXH) {
        float s = 0.f;
        for (int a = 0; a < NHEADS; ++a) s += at[a * 8 + t];
        wout[(size_t)cell * MAXH + t] = s * 0.125f;
    }

#pragma unroll
    for (int i = 0; i < 3; ++i) {
        const int d = t + i * 256;
        const int a = d / DHEAD;
        float s = 0.f;
#pragma unroll
        for (int j = 0; j < MAXH; ++j)
            s += at[a * 8 + j] * __bfloat162float(HKV[(size_t)ids[j] * 1536 + DIM + d]);
        ctx[(size_t)cell * DIM + d] = __float2bfloat16(s);
    }
}

// ---------------------------------------------------------------------------
// LayerNorm + ReLU + has-select, IN-PLACE on io (h -> enriched, fp32).
// ---------------------------------------------------------------------------
__global__ __launch_bounds__(256) void ln_kernel(
    float* io, const int* __restrict__ map,
    const float* __restrict__ ce, const int* __restrict__ pos,
    const float* __restrict__ re, const float* __restrict__ co,
    const float* __restrict__ g, const float* __restrict__ b)
{
    const int cell = blockIdx.x;
    const int t = threadIdx.x;
    __shared__ float rs[256], rq[256];
    __shared__ int hasf;
    if (t == 0) hasf = 0;

    float* hp = io + (size_t)cell * DIM;
    float v[3];
    float s = 0.f, q2 = 0.f;
#pragma unroll
    for (int i = 0; i < 3; ++i) {
        v[i] = hp[t + i * 256];
        s += v[i]; q2 += v[i] * v[i];
    }
    rs[t] = s; rq[t] = q2;
    __syncthreads();
    if (t < MAXH && map[cell * MAXH + t] >= 0) hasf = 1;
    for (int off = 128; off > 0; off >>= 1) {
        if (t < off) { rs[t] += rs[t + off]; rq[t] += rq[t + off]; }
        __syncthreads();
    }
    const float mu  = rs[0] * (1.f / 768.f);
    const float var = rq[0] * (1.f / 768.f) - mu * mu;
    const float inv = rsqrtf(var + 1e-5f);

    if (hasf) {
#pragma unroll
        for (int i = 0; i < 3; ++i) {
            const int d = t + i * 256;
            float val = (v[i] - mu) * inv * g[d] + b[d];
            hp[d] = fmaxf(val, 0.f);
        }
    } else {
        int pr = pos[cell * 2 + 0]; pr = min(max(pr, 0), 99);
        int pc = pos[cell * 2 + 1]; pc = min(max(pc, 0), 99);
#pragma unroll
        for (int i = 0; i < 3; ++i) {
            const int d = t + i * 256;
            hp[d] = ce[(size_t)cell * DIM + d] + re[(size_t)pr * DIM + d]
                  + co[(size_t)pc * DIM + d];
        }
    }
}

// ===========================================================================
// FALLBACK (verified R5 fast path) — only used if ws_size < 56.6 MB.
// ===========================================================================
template <int AMODE, int CMODE>
__global__ __launch_bounds__(256) void gemm128(
    const float* A, int lda, const bf16* A2,
    const float* __restrict__ ce, const float* __restrict__ re,
    const float* __restrict__ co, const int* __restrict__ pos,
    const float* __restrict__ W, int ldw,
    const float* __restrict__ bias,
    float* Cf, bf16* Cb, int ldc, int K)
{
    __shared__ short As[128 * 40];
    __shared__ short Bs[128 * 40];
    const int tid = threadIdx.x, wave = tid >> 6, lane = tid & 63;
    const int m0 = blockIdx.x * 128, n0 = blockIdx.y * 128;
    const int wr = (wave & 1) * 64;
    const int wc = (wave >> 1) * 64;
    const int fr = lane & 15, fk = (lane >> 4) * 8;
    const int sr = tid >> 1;
    const int sk = (tid & 1) * 16;

    int pr = 0, pc = 0;
    if (AMODE != 0) {
        const int row = m0 + sr;
        pr = pos[row * 2 + 0]; pr = min(max(pr, 0), 99);
        pc = pos[row * 2 + 1]; pc = min(max(pc, 0), 99);
    }

    floatx4 acc[16];
#pragma unroll
    for (int i = 0; i < 16; ++i) acc[i] = (floatx4){0.f, 0.f, 0.f, 0.f};

    for (int k0 = 0; k0 < K; k0 += 32) {
        short8 a_lo, a_hi;
        if (AMODE == 0) {
            a_lo = ld8(A + (size_t)(m0 + sr) * lda + k0 + sk);
            a_hi = ld8(A + (size_t)(m0 + sr) * lda + k0 + sk + 8);
        } else if (AMODE == 1 || k0 < DIM) {
            a_lo = cwp8(ce, re, co, m0 + sr, pr, pc, k0 + sk);
            a_hi = cwp8(ce, re, co, m0 + sr, pr, pc, k0 + sk + 8);
        } else {
            a_lo = *reinterpret_cast<const short8*>(A2 + (size_t)(m0 + sr) * DIM + (k0 - DIM) + sk);
            a_hi = *reinterpret_cast<const short8*>(A2 + (size_t)(m0 + sr) * DIM + (k0 - DIM) + sk + 8);
        }
        short8 b_lo = ld8(W + (size_t)(n0 + sr) * ldw + k0 + sk);
        short8 b_hi = ld8(W + (size_t)(n0 + sr) * ldw + k0 + sk + 8);

        __syncthreads();
        *reinterpret_cast<short8*>(&As[sr * 40 + sk])     = a_lo;
        *reinterpret_cast<short8*>(&As[sr * 40 + sk + 8]) = a_hi;
        *reinterpret_cast<short8*>(&Bs[sr * 40 + sk])     = b_lo;
        *reinterpret_cast<short8*>(&Bs[sr * 40 + sk + 8]) = b_hi;
        __syncthreads();

        short8 af[4], bfv[4];
#pragma unroll
        for (int i = 0; i < 4; ++i) {
            af[i]  = *reinterpret_cast<const short8*>(&As[(wr + i * 16 + fr) * 40 + fk]);
            bfv[i] = *reinterpret_cast<const short8*>(&Bs[(wc + i * 16 + fr) * 40 + fk]);
        }
#pragma unroll
        for (int i = 0; i < 4; ++i)
#pragma unroll
            for (int j = 0; j < 4; ++j)
                acc[i * 4 + j] = __builtin_amdgcn_mfma_f32_16x16x32_bf16(
                    af[i], bfv[j], acc[i * 4 + j], 0, 0, 0);
    }

    const int col_l = lane & 15, row_q = (lane >> 4) * 4;
#pragma unroll
    for (int j = 0; j < 4; ++j) {
        const int col = n0 + wc + j * 16 + col_l;
        const float bv = bias[col];
#pragma unroll
        for (int i = 0; i < 4; ++i) {
#pragma unroll
            for (int r = 0; r < 4; ++r) {
                const int row = m0 + wr + i * 16 + row_q + r;
                const float v = acc[i * 4 + j][r] + bv;
                if (CMODE == 0) Cf[(size_t)row * ldc + col] = v;
                else            Cb[(size_t)row * ldc + col] = __float2bfloat16(v);
            }
        }
    }
}

__global__ __launch_bounds__(256) void attn_kernel(
    float* io, const bf16* __restrict__ HKV, const int* __restrict__ map,
    float* __restrict__ wout)
{
    const int cell = blockIdx.x;
    const int t = threadIdx.x;
    __shared__ float qs[DIM];
    __shared__ float sc[64];
    __shared__ float at[64];
    __shared__ int   ids[MAXH];
    __shared__ float msk[MAXH];

    if (t < MAXH) {
        int id = map[cell * MAXH + t];
        msk[t] = (id >= 0) ? 1.f : 0.f;
        ids[t] = (id >= 0) ? id : 0;
    }
    for (int d = t; d < DIM; d += 256)
        qs[d] = io[(size_t)cell * DIM + d];
    __syncthreads();

    if (t < 64) {
        const int a = t >> 3, j = t & 7;
        const bf16* kp = HKV + (size_t)ids[j] * 1536 + a * DHEAD;
        float s = 0.f;
        for (int d = 0; d < DHEAD; ++d)
            s += qs[a * DHEAD + d] * __bfloat162float(kp[d]);
        s *= 0.10206207261596577f;
        sc[t] = (msk[j] != 0.f) ? s : -1e9f;
    }
    __syncthreads();

    if (t < NHEADS) {
        float m = -3e38f;
        for (int j = 0; j < MAXH; ++j) m = fmaxf(m, sc[t * 8 + j]);
        float e[MAXH]; float sum = 0.f;
        for (int j = 0; j < MAXH; ++j) { e[j] = expf(sc[t * 8 + j] - m); sum += e[j]; }
        const float inv = 1.f / sum;
        for (int j = 0; j < MAXH; ++j)
            at[t * 8 + j] = (msk[j] != 0.f) ? e[j] * inv : 0.f;
    }
    __syncthreads();

    if (t < MAXH) {
        float s = 0.f;
        for (int a = 0; a < NHEADS; ++a) s += at[a * 8 + t];
        wout[(size_t)cell * MAXH + t] = s * 0.125f;
    }

    for (int d = t; d < DIM; d += 256) {
        const int a = d / DHEAD;
        float s = 0.f;
#pragma unroll
        for (int j = 0; j < MAXH; ++j)
            s += at[a * 8 + j] * __bfloat162float(HKV[(size_t)ids[j] * 1536 + DIM + d]);
        io[(size_t)cell * DIM + d] = s;
    }
}

// ---------------------------------------------------------------------------
extern "C" void kernel_launch(void* const* d_in, const int* in_sizes, int n_in,
                              void* d_out, int out_size, void* d_ws, size_t ws_size,
                              hipStream_t stream) {
    (void)in_sizes; (void)n_in; (void)out_size;

    const float* cell_emb  = (const float*)d_in[0];
    const float* hdr_emb   = (const float*)d_in[1];
    const int*   map       = (const int*)d_in[2];
    const int*   pos       = (const int*)d_in[3];
    const float* in_proj_w = (const float*)d_in[4];   // [2304, 768]
    const float* in_proj_b = (const float*)d_in[5];
    const float* out_w     = (const float*)d_in[6];   // [768, 768]
    const float* out_b     = (const float*)d_in[7];
    const float* row_emb   = (const float*)d_in[8];
    const float* col_emb   = (const float*)d_in[9];
    const float* fus_w     = (const float*)d_in[10];  // [768, 1536]
    const float* fus_b     = (const float*)d_in[11];
    const float* ln_g      = (const float*)d_in[12];
    const float* ln_b      = (const float*)d_in[13];
    float* out = (float*)d_out;

    // ws layout (bytes):
    //   HKV   bf16 [512,1536]  @ 0          ( 1,572,864)
    //   att_b bf16 [16384,768] @ 1572864    (25,165,824)
    //   cwp_b bf16 [16384,768] @ 26738688   (25,165,824)
    //   Wq_b  bf16 [768,768]   @ 51904512   ( 1,179,648)
    //   Wo_b  bf16 [768,768]   @ 53084160   ( 1,179,648)
    //   Wf_b  bf16 [768,1536]  @ 54263808   ( 2,359,296)  -> total 56,623,104
    char* ws = (char*)d_ws;
    bf16* HKV    = (bf16*)ws;
    bf16* att_b  = (bf16*)(ws + 1572864);
    bf16* cwp_b  = (bf16*)(ws + 26738688);
    bf16* Wq_b   = (bf16*)(ws + 51904512);
    bf16* Wo_b   = (bf16*)(ws + 53084160);
    bf16* Wf_b   = (bf16*)(ws + 54263808);
    // d_out raw-byte scratch: q_b bf16 @ [0,25165824), ctx_b @ [25165824,50331648)
    bf16* q_b    = (bf16*)d_out;
    bf16* ctx_b  = (bf16*)((char*)d_out + 25165824);

    // 1. HKV = headers @ [Wk;Wv]^T + [bk;bv]  (fp32 in, bf16 out)
    gemm_hkv<<<dim3(8, 24), 256, 0, stream>>>(
        hdr_emb, DIM, in_proj_w + (size_t)DIM * DIM, DIM, in_proj_b + DIM,
        HKV, 1536, DIM);

    if (ws_size >= 56623104) {
        // 2. one-time bf16 conversions
        cwp_b_kernel<<<NCELLS, 256, 0, stream>>>(cell_emb, pos, row_emb, col_emb, cwp_b);
        cvt_kernel<<<(589824 / 4 + 255) / 256, 256, 0, stream>>>(in_proj_w, Wq_b, 589824 / 4);
        cvt_kernel<<<(589824 / 4 + 255) / 256, 256, 0, stream>>>(out_w, Wo_b, 589824 / 4);
        cvt_kernel<<<(1179648 / 4 + 255) / 256, 256, 0, stream>>>(fus_w, Wf_b, 1179648 / 4);

        // 3. q_b = cwp_b @ Wq_b^T + bq  (bf16 out -> d_out bytes [0,25MB))
        gemm_bf<0, 1><<<768, 256, 0, stream>>>(
            cwp_b, nullptr, Wq_b, DIM, in_proj_b, nullptr, q_b, DIM);

        // 4. attention: q_b -> ctx_b; weights -> d_out tail (fp32)
        attn_b_kernel<<<NCELLS, 256, 0, stream>>>(q_b, ctx_b, HKV, map, out + ND);

        // 5. att_b = ctx_b @ Wo_b^T + out_b  (bf16 out -> ws)
        gemm_bf<0, 1><<<768, 256, 0, stream>>>(
            ctx_b, nullptr, Wo_b, DIM, out_b, nullptr, att_b, DIM);

        // 6. h = [cwp_b | att_b] @ Wf_b^T + fus_b  (fp32 out -> d_out; q_b/ctx_b dead)
        gemm_bf<1, 0><<<768, 256, 0, stream>>>(
            cwp_b, att_b, Wf_b, 1536, fus_b, out, nullptr, 1536);
    } else {
        // Fallback: verified R5 fast path (needs 26,738,688 B of ws)
        bf16* att_bf = (bf16*)(ws + 1572864);
        gemm128<1, 0><<<dim3(NCELLS / 128, DIM / 128), 256, 0, stream>>>(
            nullptr, 0, nullptr, cell_emb, row_emb, col_emb, pos,
            in_proj_w, DIM, in_proj_b, out, nullptr, DIM, DIM);
        attn_kernel<<<NCELLS, 256, 0, stream>>>(out, HKV, map, out + ND);
        gemm128<0, 1><<<dim3(NCELLS / 128, DIM / 128), 256, 0, stream>>>(
            out, DIM, nullptr, nullptr, nullptr, nullptr, nullptr,
            out_w, DIM, out_b, nullptr, att_bf, DIM, DIM);
        gemm128<2, 0><<<dim3(NCELLS / 128, DIM / 128), 256, 0, stream>>>(
            nullptr, 0, att_bf, cell_emb, row_emb, col_emb, pos,
            fus_w, 1536, fus_b, out, nullptr, DIM, 1536);
    }

    // 7. LayerNorm + ReLU + select (in-place on d_out fp32)
    ln_kernel<<<NCELLS, 256, 0, stream>>>(out, map, cell_emb, pos,
                                          row_emb, col_emb, ln_g, ln_b);
}

// Round 8
// 316.627 us; speedup vs baseline: 1.7550x; 1.0163x over previous
//
#include <hip/hip_runtime.h>
#include <hip/hip_bf16.h>

// Problem constants (fixed by reference)
#define NCELLS 16384
#define DIM    768
#define NHEADS 8
#define DHEAD  96           // 768/8
#define MAXH   8
#define ND     (NCELLS * DIM)          // 12582912

// ALL float tensors are fp32 I/O (reference uses jnp.float32 throughout).
// Internal compute: bf16 operands + MFMA, fp32 accumulate/output.

using bf16 = __hip_bfloat16;
typedef short  short8  __attribute__((ext_vector_type(8)));
typedef short  short4v __attribute__((ext_vector_type(4)));
typedef float  floatx4 __attribute__((ext_vector_type(4)));

__device__ inline short f2b(float f) {
    bf16 h = __float2bfloat16(f);
    unsigned short u; __builtin_memcpy(&u, &h, 2); return (short)u;
}
__device__ inline float b2f(short u) {
    unsigned x = ((unsigned)(unsigned short)u) << 16;
    float f; __builtin_memcpy(&f, &x, 4); return f;
}

// load 8 consecutive fp32, convert to 8 bf16
__device__ inline short8 ld8(const float* p) {
    floatx4 a = *reinterpret_cast<const floatx4*>(p);
    floatx4 b = *reinterpret_cast<const floatx4*>(p + 4);
    short8 o;
#pragma unroll
    for (int i = 0; i < 4; ++i) { o[i] = f2b(a[i]); o[i + 4] = f2b(b[i]); }
    return o;
}

// async 16B global -> LDS (direct DMA, no VGPR round-trip). Destination is
// wave-uniform base + lane*16 (m104/m108): pass per-lane addr; lane0 = base.
__device__ __forceinline__ void cp16(const void* g, void* l) {
    __builtin_amdgcn_global_load_lds(
        (const __attribute__((address_space(1))) void*)g,
        (__attribute__((address_space(3))) void*)l, 16, 0, 0);
}

// ===========================================================================
// Pure-bf16 GEMM, 128x128 tile, BK=64, 256 thr (4 waves, 2x2), staging via
// global_load_lds width=16. XCD-swizzled linear grid: mb=id&127, nb=id>>7.
// LDS tiles UNPADDED [128][64]; bank conflicts broken by XOR-swizzling the
// k-group with row&7 on the GLOBAL source address + matching XOR on ds_read.
// Measured R7: 0 bank conflicts, fusion (K=1536) ~54.5 us (~710 TF).
// DUAL=1: A spans K=1536 as [A | A2]. COUT: 0=f32 C, 1=bf16 C.
// ===========================================================================
template <int DUAL, int COUT>
__global__ __launch_bounds__(256) void gemm_bf(
    const bf16* __restrict__ A, const bf16* __restrict__ A2,
    const bf16* __restrict__ W, int ldw,
    const float* __restrict__ bias,
    float* __restrict__ Cf, bf16* __restrict__ Cb, int K)
{
    __shared__ short As[128 * 64];   // 16,384 B
    __shared__ short Bs[128 * 64];   // 16,384 B
    const int tid = threadIdx.x, wave = tid >> 6, lane = tid & 63;
    const int id = blockIdx.x;
    const int m0 = (id & 127) * 128;
    const int n0 = (id >> 7) * 128;
    const int wr = (wave & 1) * 64, wc = (wave >> 1) * 64;
    const int fr = lane & 15, kg = lane >> 4;   // fragment row / k-group

    const int srow = lane >> 3;            // row within chunk (== row&7)
    const int scol = (lane & 7) ^ srow;    // swizzled source k-group

    floatx4 acc[16];
#pragma unroll
    for (int i = 0; i < 16; ++i) acc[i] = (floatx4){0.f, 0.f, 0.f, 0.f};

    for (int k0 = 0; k0 < K; k0 += 64) {
        const bf16* Ak; int ka;
        if (!DUAL || k0 < DIM) { Ak = A;  ka = k0; }
        else                   { Ak = A2; ka = k0 - DIM; }

        __syncthreads();   // previous iteration's ds_reads complete
#pragma unroll
        for (int i = 0; i < 4; ++i) {
            const int c = i * 4 + wave;
            const int row = c * 8 + srow;
            cp16(Ak + (size_t)(m0 + row) * DIM + ka + scol * 8,
                 &As[c * 512 + lane * 8]);
            cp16(W  + (size_t)(n0 + row) * ldw + k0 + scol * 8,
                 &Bs[c * 512 + lane * 8]);
        }
        __syncthreads();   // vmcnt(0) drained: tiles landed

#pragma unroll
        for (int kk = 0; kk < 2; ++kk) {
            short8 af[4], bfv[4];
#pragma unroll
            for (int i = 0; i < 4; ++i) {
                const int sa = ((kk * 4 + kg) ^ (fr & 7)) * 8;
                af[i]  = *reinterpret_cast<const short8*>(&As[(wr + i * 16 + fr) * 64 + sa]);
                bfv[i] = *reinterpret_cast<const short8*>(&Bs[(wc + i * 16 + fr) * 64 + sa]);
            }
#pragma unroll
            for (int i = 0; i < 4; ++i)
#pragma unroll
                for (int j = 0; j < 4; ++j)
                    acc[i * 4 + j] = __builtin_amdgcn_mfma_f32_16x16x32_bf16(
                        af[i], bfv[j], acc[i * 4 + j], 0, 0, 0);
        }
    }

    const int col_l = lane & 15, row_q = kg * 4;
#pragma unroll
    for (int j = 0; j < 4; ++j) {
        const int col = n0 + wc + j * 16 + col_l;
        const float bv = bias[col];
#pragma unroll
        for (int i = 0; i < 4; ++i) {
#pragma unroll
            for (int r = 0; r < 4; ++r) {
                const int row = m0 + wr + i * 16 + row_q + r;
                const float v = acc[i * 4 + j][r] + bv;
                if (COUT == 0) Cf[(size_t)row * DIM + col] = v;
                else           Cb[(size_t)row * DIM + col] = __float2bfloat16(v);
            }
        }
    }
}

// ---------------------------------------------------------------------------
// cwp_b = bf16(ce + re[pr] + co[pc]) [N,768], chunk-parallel & vectorized:
// thread -> one 8-elem chunk: 6x float4 in, 1x short8 out. 96 chunks/cell.
// grid = NCELLS*96/256 = 6144 blocks.
// ---------------------------------------------------------------------------
__global__ __launch_bounds__(256) void cwp_v_kernel(
    const float* __restrict__ ce, const int* __restrict__ pos,
    const float* __restrict__ re, const float* __restrict__ co,
    bf16* __restrict__ dst)
{
    const int gid  = blockIdx.x * 256 + threadIdx.x;
    const int cell = gid / 96;
    const int off  = (gid % 96) * 8;
    int pr = pos[cell * 2 + 0]; pr = min(max(pr, 0), 99);
    int pc = pos[cell * 2 + 1]; pc = min(max(pc, 0), 99);
    const float* a = ce + (size_t)cell * DIM + off;
    const float* b = re + (size_t)pr * DIM + off;
    const float* c = co + (size_t)pc * DIM + off;
    floatx4 a0 = *reinterpret_cast<const floatx4*>(a);
    floatx4 a1 = *reinterpret_cast<const floatx4*>(a + 4);
    floatx4 b0 = *reinterpret_cast<const floatx4*>(b);
    floatx4 b1 = *reinterpret_cast<const floatx4*>(b + 4);
    floatx4 c0 = *reinterpret_cast<const floatx4*>(c);
    floatx4 c1 = *reinterpret_cast<const floatx4*>(c + 4);
    short8 o;
#pragma unroll
    for (int i = 0; i < 4; ++i) {
        o[i]     = f2b(a0[i] + b0[i] + c0[i]);
        o[i + 4] = f2b(a1[i] + b1[i] + c1[i]);
    }
    *reinterpret_cast<short8*>((short*)dst + (size_t)cell * DIM + off) = o;
}

// ---------------------------------------------------------------------------
// fp32 -> bf16 elementwise (weights), vectorized 4-wide. n % 1024 == 0.
// ---------------------------------------------------------------------------
__global__ __launch_bounds__(256) void cvt_kernel(
    const float* __restrict__ src, bf16* __restrict__ dst, int n4)
{
    const int i = blockIdx.x * 256 + threadIdx.x;
    if (i >= n4) return;
    floatx4 v = *reinterpret_cast<const floatx4*>(src + (size_t)i * 4);
    short4v o;
#pragma unroll
    for (int j = 0; j < 4; ++j) o[j] = f2b(v[j]);
    *reinterpret_cast<short4v*>((short*)dst + (size_t)i * 4) = o;
}

// ---------------------------------------------------------------------------
// HKV GEMM: C_bf16[512,1536] = hdr_f32 @ Wkv_f32^T + bias. 256 thr, 64x64.
// ---------------------------------------------------------------------------
__global__ __launch_bounds__(256) void gemm_hkv(
    const float* __restrict__ A, int lda,
    const float* __restrict__ W, int ldw,
    const float* __restrict__ bias,
    bf16* __restrict__ C, int ldc, int K)
{
    __shared__ short As[64 * 40];
    __shared__ short Bs[64 * 40];
    const int tid = threadIdx.x, wave = tid >> 6, lane = tid & 63;
    const int m0 = blockIdx.x * 64, n0 = blockIdx.y * 64;
    const int lr = tid >> 2, lc = (tid & 3) * 8;
    const int fr = lane & 15, fk = (lane >> 4) * 8;

    floatx4 acc[4];
#pragma unroll
    for (int i = 0; i < 4; ++i) acc[i] = (floatx4){0.f, 0.f, 0.f, 0.f};

    for (int k0 = 0; k0 < K; k0 += 32) {
        short8 av = ld8(A + (size_t)(m0 + lr) * lda + k0 + lc);
        short8 wv = ld8(W + (size_t)(n0 + lr) * ldw + k0 + lc);
        __syncthreads();
        *reinterpret_cast<short8*>(&As[lr * 40 + lc]) = av;
        *reinterpret_cast<short8*>(&Bs[lr * 40 + lc]) = wv;
        __syncthreads();
        short8 af = *reinterpret_cast<const short8*>(&As[(wave * 16 + fr) * 40 + fk]);
#pragma unroll
        for (int t = 0; t < 4; ++t) {
            short8 bfv = *reinterpret_cast<const short8*>(&Bs[(t * 16 + fr) * 40 + fk]);
            acc[t] = __builtin_amdgcn_mfma_f32_16x16x32_bf16(af, bfv, acc[t], 0, 0, 0);
        }
    }
    const int col_l = lane & 15, row_q = (lane >> 4) * 4;
#pragma unroll
    for (int t = 0; t < 4; ++t) {
        const int col = n0 + t * 16 + col_l;
        const float bv = bias[col];
#pragma unroll
        for (int r = 0; r < 4; ++r) {
            const int row = m0 + wave * 16 + row_q + r;
            C[(size_t)row * ldc + col] = __float2bfloat16(acc[t][r] + bv);
        }
    }
}

// ---------------------------------------------------------------------------
// Vectorized per-cell attention. Block = 128 thr (2 waves), 1 cell/block.
// All q/HKV/ctx traffic as short8 (16 B): K-dot = 12 vec loads per
// (head,slot) pair; V-accum = 8 vec loads per 8-dim chunk; vec ctx stores.
// ---------------------------------------------------------------------------
__global__ __launch_bounds__(128) void attn_v_kernel(
    const bf16* __restrict__ q, bf16* __restrict__ ctx,
    const bf16* __restrict__ HKV, const int* __restrict__ map,
    float* __restrict__ wout)
{
    const int cell = blockIdx.x;
    const int t = threadIdx.x;
    __shared__ float qs[DIM];
    __shared__ float sc[64];
    __shared__ float at[64];
    __shared__ int   ids[MAXH];
    __shared__ float msk[MAXH];

    if (t < MAXH) {
        int id = map[cell * MAXH + t];
        msk[t] = (id >= 0) ? 1.f : 0.f;
        ids[t] = (id >= 0) ? id : 0;
    }
    if (t < 96) {  // stage q: 96 x short8
        short8 qv = *reinterpret_cast<const short8*>((const short*)q + (size_t)cell * DIM + t * 8);
#pragma unroll
        for (int e = 0; e < 8; ++e) qs[t * 8 + e] = b2f(qv[e]);
    }
    __syncthreads();

    if (t < 64) {  // scores: head a = t>>3, slot j = t&7
        const int a = t >> 3, j = t & 7;
        const short* kp = (const short*)HKV + (size_t)ids[j] * 1536 + a * DHEAD;
        float s = 0.f;
#pragma unroll
        for (int c = 0; c < 12; ++c) {
            short8 kv = *reinterpret_cast<const short8*>(kp + c * 8);
#pragma unroll
            for (int e = 0; e < 8; ++e)
                s += qs[a * DHEAD + c * 8 + e] * b2f(kv[e]);
        }
        s *= 0.10206207261596577f;  // 1/sqrt(96)
        sc[t] = (msk[j] != 0.f) ? s : -1e9f;
    }
    __syncthreads();

    if (t < NHEADS) {  // softmax per head
        float m = -3e38f;
        for (int j = 0; j < MAXH; ++j) m = fmaxf(m, sc[t * 8 + j]);
        float e[MAXH]; float sum = 0.f;
        for (int j = 0; j < MAXH; ++j) { e[j] = expf(sc[t * 8 + j] - m); sum += e[j]; }
        const float inv = 1.f / sum;
        for (int j = 0; j < MAXH; ++j)
            at[t * 8 + j] = (msk[j] != 0.f) ? e[j] * inv : 0.f;
    }
    __syncthreads();

    if (t < MAXH) {  // head-averaged weights
        float s = 0.f;
        for (int a = 0; a < NHEADS; ++a) s += at[a * 8 + t];
        wout[(size_t)cell * MAXH + t] = s * 0.125f;
    }

    if (t < 96) {  // ctx: dims [t*8, t*8+8), head a = t/12
        const int a = t / 12, d0 = t * 8;
        float acc[8];
#pragma unroll
        for (int e = 0; e < 8; ++e) acc[e] = 0.f;
#pragma unroll
        for (int j = 0; j < MAXH; ++j) {
            short8 vv = *reinterpret_cast<const short8*>(
                (const short*)HKV + (size_t)ids[j] * 1536 + DIM + d0);
            const float w = at[a * 8 + j];
#pragma unroll
            for (int e = 0; e < 8; ++e) acc[e] += w * b2f(vv[e]);
        }
        short8 o;
#pragma unroll
        for (int e = 0; e < 8; ++e) o[e] = f2b(acc[e]);
        *reinterpret_cast<short8*>((short*)ctx + (size_t)cell * DIM + d0) = o;
    }
}

// ---------------------------------------------------------------------------
// LayerNorm + ReLU + has-select, IN-PLACE, vectorized. Block = 192 thr
// (3 waves), float4 per thread (192*4 = 768). Wave-shuffle reduction.
// ---------------------------------------------------------------------------
__global__ __launch_bounds__(192) void ln_v_kernel(
    float* io, const int* __restrict__ map,
    const float* __restrict__ ce, const int* __restrict__ pos,
    const float* __restrict__ re, const float* __restrict__ co,
    const float* __restrict__ g, const float* __restrict__ b)
{
    const int cell = blockIdx.x;
    const int t = threadIdx.x;
    const int wave = t >> 6, lane = t & 63;
    __shared__ float ws_[3], wq_[3];
    __shared__ int hasf;
    if (t == 0) hasf = 0;

    float* hp = io + (size_t)cell * DIM;
    floatx4 v = *reinterpret_cast<const floatx4*>(hp + t * 4);
    float s  = v[0] + v[1] + v[2] + v[3];
    float q2 = v[0]*v[0] + v[1]*v[1] + v[2]*v[2] + v[3]*v[3];
#pragma unroll
    for (int off = 32; off > 0; off >>= 1) {
        s  += __shfl_down(s, off);
        q2 += __shfl_down(q2, off);
    }
    __syncthreads();           // hasf init visible
    if (t < MAXH && map[cell * MAXH + t] >= 0) hasf = 1;
    if (lane == 0) { ws_[wave] = s; wq_[wave] = q2; }
    __syncthreads();

    const float mu  = (ws_[0] + ws_[1] + ws_[2]) * (1.f / 768.f);
    const float var = (wq_[0] + wq_[1] + wq_[2]) * (1.f / 768.f) - mu * mu;
    const float inv = rsqrtf(var + 1e-5f);

    if (hasf) {
        floatx4 gv = *reinterpret_cast<const floatx4*>(g + t * 4);
        floatx4 bv = *reinterpret_cast<const floatx4*>(b + t * 4);
        floatx4 o;
#pragma unroll
        for (int e = 0; e < 4; ++e)
            o[e] = fmaxf((v[e] - mu) * inv * gv[e] + bv[e], 0.f);
        *reinterpret_cast<floatx4*>(hp + t * 4) = o;
    } else {
        int pr = pos[cell * 2 + 0]; pr = min(max(pr, 0), 99);
        int pc = pos[cell * 2 + 1]; pc = min(max(pc, 0), 99);
        floatx4 a0 = *reinterpret_cast<const floatx4*>(ce + (size_t)cell * DIM + t * 4);
        floatx4 b0 = *reinterpret_cast<const floatx4*>(re + (size_t)pr * DIM + t * 4);
        floatx4 c0 = *reinterpret_cast<const floatx4*>(co + (size_t)pc * DIM + t * 4);
        floatx4 o;
#pragma unroll
        for (int e = 0; e < 4; ++e) o[e] = a0[e] + b0[e] + c0[e];
        *reinterpret_cast<floatx4*>(hp + t * 4) = o;
    }
}

// ---------------------------------------------------------------------------
extern "C" void kernel_launch(void* const* d_in, const int* in_sizes, int n_in,
                              void* d_out, int out_size, void* d_ws, size_t ws_size,
                              hipStream_t stream) {
    (void)in_sizes; (void)n_in; (void)out_size; (void)ws_size;

    const float* cell_emb  = (const float*)d_in[0];
    const float* hdr_emb   = (const float*)d_in[1];
    const int*   map       = (const int*)d_in[2];
    const int*   pos       = (const int*)d_in[3];
    const float* in_proj_w = (const float*)d_in[4];   // [2304, 768]
    const float* in_proj_b = (const float*)d_in[5];
    const float* out_w     = (const float*)d_in[6];   // [768, 768]
    const float* out_b     = (const float*)d_in[7];
    const float* row_emb   = (const float*)d_in[8];
    const float* col_emb   = (const float*)d_in[9];
    const float* fus_w     = (const float*)d_in[10];  // [768, 1536]
    const float* fus_b     = (const float*)d_in[11];
    const float* ln_g      = (const float*)d_in[12];
    const float* ln_b      = (const float*)d_in[13];
    float* out = (float*)d_out;

    // ws layout (bytes) — total 56,623,104 (proven available: R6/R7 fast path):
    //   HKV   bf16 [512,1536]  @ 0          ( 1,572,864)
    //   att_b bf16 [16384,768] @ 1572864    (25,165,824)
    //   cwp_b bf16 [16384,768] @ 26738688   (25,165,824)
    //   Wq_b  bf16 [768,768]   @ 51904512   ( 1,179,648)
    //   Wo_b  bf16 [768,768]   @ 53084160   ( 1,179,648)
    //   Wf_b  bf16 [768,1536]  @ 54263808   ( 2,359,296)
    char* ws = (char*)d_ws;
    bf16* HKV    = (bf16*)ws;
    bf16* att_b  = (bf16*)(ws + 1572864);
    bf16* cwp_b  = (bf16*)(ws + 26738688);
    bf16* Wq_b   = (bf16*)(ws + 51904512);
    bf16* Wo_b   = (bf16*)(ws + 53084160);
    bf16* Wf_b   = (bf16*)(ws + 54263808);
    // d_out raw-byte scratch: q_b bf16 @ [0,25165824), ctx_b @ [25165824,50331648)
    bf16* q_b    = (bf16*)d_out;
    bf16* ctx_b  = (bf16*)((char*)d_out + 25165824);

    // 1. HKV = headers @ [Wk;Wv]^T + [bk;bv]  (fp32 in, bf16 out)
    gemm_hkv<<<dim3(8, 24), 256, 0, stream>>>(
        hdr_emb, DIM, in_proj_w + (size_t)DIM * DIM, DIM, in_proj_b + DIM,
        HKV, 1536, DIM);

    // 2. one-time bf16 conversions
    cwp_v_kernel<<<NCELLS * 96 / 256, 256, 0, stream>>>(
        cell_emb, pos, row_emb, col_emb, cwp_b);
    cvt_kernel<<<(589824 / 4 + 255) / 256, 256, 0, stream>>>(in_proj_w, Wq_b, 589824 / 4);
    cvt_kernel<<<(589824 / 4 + 255) / 256, 256, 0, stream>>>(out_w, Wo_b, 589824 / 4);
    cvt_kernel<<<(1179648 / 4 + 255) / 256, 256, 0, stream>>>(fus_w, Wf_b, 1179648 / 4);

    // 3. q_b = cwp_b @ Wq_b^T + bq  (bf16 out -> d_out bytes [0,25MB))
    gemm_bf<0, 1><<<768, 256, 0, stream>>>(
        cwp_b, nullptr, Wq_b, DIM, in_proj_b, nullptr, q_b, DIM);

    // 4. attention: q_b -> ctx_b; weights -> d_out tail (fp32)
    attn_v_kernel<<<NCELLS, 128, 0, stream>>>(q_b, ctx_b, HKV, map, out + ND);

    // 5. att_b = ctx_b @ Wo_b^T + out_b  (bf16 out -> ws)
    gemm_bf<0, 1><<<768, 256, 0, stream>>>(
        ctx_b, nullptr, Wo_b, DIM, out_b, nullptr, att_b, DIM);

    // 6. h = [cwp_b | att_b] @ Wf_b^T + fus_b  (fp32 out -> d_out; q/ctx dead)
    gemm_bf<1, 0><<<768, 256, 0, stream>>>(
        cwp_b, att_b, Wf_b, 1536, fus_b, out, nullptr, 1536);

    // 7. LayerNorm + ReLU + select (in-place on d_out fp32)
    ln_v_kernel<<<NCELLS, 192, 0, stream>>>(out, map, cell_emb, pos,
                                            row_emb, col_emb, ln_g, ln_b);
}

// Round 9
// 306.822 us; speedup vs baseline: 1.8111x; 1.0320x over previous
//
#include <hip/hip_runtime.h>
#include <hip/hip_bf16.h>

// Problem constants (fixed by reference)
#define NCELLS 16384
#define DIM    768
#define NHEADS 8
#define DHEAD  96           // 768/8
#define MAXH   8
#define ND     (NCELLS * DIM)          // 12582912

// ALL float tensors are fp32 I/O (reference uses jnp.float32 throughout).
// Internal compute: bf16 operands + MFMA, fp32 accumulate/output.

using bf16 = __hip_bfloat16;
typedef short  short8  __attribute__((ext_vector_type(8)));
typedef short  short4v __attribute__((ext_vector_type(4)));
typedef float  floatx4 __attribute__((ext_vector_type(4)));

__device__ inline short f2b(float f) {
    bf16 h = __float2bfloat16(f);
    unsigned short u; __builtin_memcpy(&u, &h, 2); return (short)u;
}
__device__ inline float b2f(short u) {
    unsigned x = ((unsigned)(unsigned short)u) << 16;
    float f; __builtin_memcpy(&f, &x, 4); return f;
}

// load 8 consecutive fp32, convert to 8 bf16
__device__ inline short8 ld8(const float* p) {
    floatx4 a = *reinterpret_cast<const floatx4*>(p);
    floatx4 b = *reinterpret_cast<const floatx4*>(p + 4);
    short8 o;
#pragma unroll
    for (int i = 0; i < 4; ++i) { o[i] = f2b(a[i]); o[i + 4] = f2b(b[i]); }
    return o;
}

// async 16B global -> LDS (direct DMA, no VGPR round-trip). Destination is
// wave-uniform base + lane*16 (m104/m108): pass per-lane addr; lane0 = base.
__device__ __forceinline__ void cp16(const void* g, void* l) {
    __builtin_amdgcn_global_load_lds(
        (const __attribute__((address_space(1))) void*)g,
        (__attribute__((address_space(3))) void*)l, 16, 0, 0);
}

// ===========================================================================
// Pure-bf16 GEMM, 128x128 tile, BK=64, 256 thr (4 waves, 2x2), staging via
// global_load_lds width=16. XCD-swizzled linear grid: mb=id&127, nb=id>>7.
// LDS tiles UNPADDED [128][64]; bank conflicts broken by XOR-swizzling the
// k-group with row&7 on the GLOBAL source address + matching XOR on ds_read.
// Measured R7/R8: 0 bank conflicts, fusion (K=1536) ~52 us (~740 TF).
// DUAL=1: A spans K=1536 as [A | A2]. COUT: 0=f32 C, 1=bf16 C.
// ===========================================================================
template <int DUAL, int COUT>
__global__ __launch_bounds__(256) void gemm_bf(
    const bf16* __restrict__ A, const bf16* __restrict__ A2,
    const bf16* __restrict__ W, int ldw,
    const float* __restrict__ bias,
    float* __restrict__ Cf, bf16* __restrict__ Cb, int K)
{
    __shared__ short As[128 * 64];   // 16,384 B
    __shared__ short Bs[128 * 64];   // 16,384 B
    const int tid = threadIdx.x, wave = tid >> 6, lane = tid & 63;
    const int id = blockIdx.x;
    const int m0 = (id & 127) * 128;
    const int n0 = (id >> 7) * 128;
    const int wr = (wave & 1) * 64, wc = (wave >> 1) * 64;
    const int fr = lane & 15, kg = lane >> 4;   // fragment row / k-group

    const int srow = lane >> 3;            // row within chunk (== row&7)
    const int scol = (lane & 7) ^ srow;    // swizzled source k-group

    floatx4 acc[16];
#pragma unroll
    for (int i = 0; i < 16; ++i) acc[i] = (floatx4){0.f, 0.f, 0.f, 0.f};

    for (int k0 = 0; k0 < K; k0 += 64) {
        const bf16* Ak; int ka;
        if (!DUAL || k0 < DIM) { Ak = A;  ka = k0; }
        else                   { Ak = A2; ka = k0 - DIM; }

        __syncthreads();   // previous iteration's ds_reads complete
#pragma unroll
        for (int i = 0; i < 4; ++i) {
            const int c = i * 4 + wave;
            const int row = c * 8 + srow;
            cp16(Ak + (size_t)(m0 + row) * DIM + ka + scol * 8,
                 &As[c * 512 + lane * 8]);
            cp16(W  + (size_t)(n0 + row) * ldw + k0 + scol * 8,
                 &Bs[c * 512 + lane * 8]);
        }
        __syncthreads();   // vmcnt(0) drained: tiles landed

#pragma unroll
        for (int kk = 0; kk < 2; ++kk) {
            short8 af[4], bfv[4];
#pragma unroll
            for (int i = 0; i < 4; ++i) {
                const int sa = ((kk * 4 + kg) ^ (fr & 7)) * 8;
                af[i]  = *reinterpret_cast<const short8*>(&As[(wr + i * 16 + fr) * 64 + sa]);
                bfv[i] = *reinterpret_cast<const short8*>(&Bs[(wc + i * 16 + fr) * 64 + sa]);
            }
#pragma unroll
            for (int i = 0; i < 4; ++i)
#pragma unroll
                for (int j = 0; j < 4; ++j)
                    acc[i * 4 + j] = __builtin_amdgcn_mfma_f32_16x16x32_bf16(
                        af[i], bfv[j], acc[i * 4 + j], 0, 0, 0);
        }
    }

    const int col_l = lane & 15, row_q = kg * 4;
#pragma unroll
    for (int j = 0; j < 4; ++j) {
        const int col = n0 + wc + j * 16 + col_l;
        const float bv = bias[col];
#pragma unroll
        for (int i = 0; i < 4; ++i) {
#pragma unroll
            for (int r = 0; r < 4; ++r) {
                const int row = m0 + wr + i * 16 + row_q + r;
                const float v = acc[i * 4 + j][r] + bv;
                if (COUT == 0) Cf[(size_t)row * DIM + col] = v;
                else           Cb[(size_t)row * DIM + col] = __float2bfloat16(v);
            }
        }
    }
}

// ===========================================================================
// PREP kernel: one dispatch replaces 5 (cwp_b build, cvt x3, HKV GEMM).
// Block-range roles (branch is block-uniform):
//   [0, 6144)        cwp_b  = bf16(ce + re[pr] + co[pc])   (thread = 8 elems)
//   [6144, 6720)     Wq_b   = bf16(in_proj_w[0:768*768])   (thread = 4 elems)
//   [6720, 7296)     Wo_b   = bf16(out_w)
//   [7296, 8448)     Wf_b   = bf16(fus_w)
//   [8448, 8640)     HKV    = hdr @ [Wk;Wv]^T + bias (64x64-tile MFMA GEMM)
// ===========================================================================
__global__ __launch_bounds__(256) void prep_kernel(
    const float* __restrict__ ce, const int* __restrict__ pos,
    const float* __restrict__ re, const float* __restrict__ co,
    bf16* __restrict__ cwp_b,
    const float* __restrict__ in_proj_w, bf16* __restrict__ Wq_b,
    const float* __restrict__ out_w,     bf16* __restrict__ Wo_b,
    const float* __restrict__ fus_w,     bf16* __restrict__ Wf_b,
    const float* __restrict__ hdr, const float* __restrict__ in_proj_b,
    bf16* __restrict__ HKV)
{
    __shared__ short As[64 * 40];   // used by HKV branch only (10,240 B)
    __shared__ short Bs[64 * 40];
    const int b = blockIdx.x, tid = threadIdx.x;

    if (b < 6144) {                          // ---- cwp_b ----
        const int gid  = b * 256 + tid;
        const int cell = gid / 96;
        const int off  = (gid % 96) * 8;
        int pr = pos[cell * 2 + 0]; pr = min(max(pr, 0), 99);
        int pc = pos[cell * 2 + 1]; pc = min(max(pc, 0), 99);
        const float* a = ce + (size_t)cell * DIM + off;
        const float* bb = re + (size_t)pr * DIM + off;
        const float* c = co + (size_t)pc * DIM + off;
        floatx4 a0 = *reinterpret_cast<const floatx4*>(a);
        floatx4 a1 = *reinterpret_cast<const floatx4*>(a + 4);
        floatx4 b0 = *reinterpret_cast<const floatx4*>(bb);
        floatx4 b1 = *reinterpret_cast<const floatx4*>(bb + 4);
        floatx4 c0 = *reinterpret_cast<const floatx4*>(c);
        floatx4 c1 = *reinterpret_cast<const floatx4*>(c + 4);
        short8 o;
#pragma unroll
        for (int i = 0; i < 4; ++i) {
            o[i]     = f2b(a0[i] + b0[i] + c0[i]);
            o[i + 4] = f2b(a1[i] + b1[i] + c1[i]);
        }
        *reinterpret_cast<short8*>((short*)cwp_b + (size_t)cell * DIM + off) = o;
    } else if (b < 8448) {                   // ---- weight converts ----
        const float* src; bf16* dst; int i;
        if (b < 6720)      { src = in_proj_w; dst = Wq_b; i = (b - 6144) * 256 + tid; }
        else if (b < 7296) { src = out_w;     dst = Wo_b; i = (b - 6720) * 256 + tid; }
        else               { src = fus_w;     dst = Wf_b; i = (b - 7296) * 256 + tid; }
        floatx4 v = *reinterpret_cast<const floatx4*>(src + (size_t)i * 4);
        short4v o;
#pragma unroll
        for (int j = 0; j < 4; ++j) o[j] = f2b(v[j]);
        *reinterpret_cast<short4v*>((short*)dst + (size_t)i * 4) = o;
    } else {                                 // ---- HKV GEMM ----
        const int b2 = b - 8448;
        const int m0 = (b2 & 7) * 64, n0 = (b2 >> 3) * 64;
        const float* W = in_proj_w + (size_t)DIM * DIM;   // [Wk;Wv]
        const float* bias = in_proj_b + DIM;
        const int wave = tid >> 6, lane = tid & 63;
        const int lr = tid >> 2, lc = (tid & 3) * 8;
        const int fr = lane & 15, fk = (lane >> 4) * 8;

        floatx4 acc[4];
#pragma unroll
        for (int i = 0; i < 4; ++i) acc[i] = (floatx4){0.f, 0.f, 0.f, 0.f};

        for (int k0 = 0; k0 < DIM; k0 += 32) {
            short8 av = ld8(hdr + (size_t)(m0 + lr) * DIM + k0 + lc);
            short8 wv = ld8(W   + (size_t)(n0 + lr) * DIM + k0 + lc);
            __syncthreads();
            *reinterpret_cast<short8*>(&As[lr * 40 + lc]) = av;
            *reinterpret_cast<short8*>(&Bs[lr * 40 + lc]) = wv;
            __syncthreads();
            short8 af = *reinterpret_cast<const short8*>(&As[(wave * 16 + fr) * 40 + fk]);
#pragma unroll
            for (int t = 0; t < 4; ++t) {
                short8 bfv = *reinterpret_cast<const short8*>(&Bs[(t * 16 + fr) * 40 + fk]);
                acc[t] = __builtin_amdgcn_mfma_f32_16x16x32_bf16(af, bfv, acc[t], 0, 0, 0);
            }
        }
        const int col_l = lane & 15, row_q = (lane >> 4) * 4;
#pragma unroll
        for (int t = 0; t < 4; ++t) {
            const int col = n0 + t * 16 + col_l;
            const float bv = bias[col];
#pragma unroll
            for (int r = 0; r < 4; ++r) {
                const int row = m0 + wave * 16 + row_q + r;
                HKV[(size_t)row * 1536 + col] = __float2bfloat16(acc[t][r] + bv);
            }
        }
    }
}

// ---------------------------------------------------------------------------
// Vectorized attention, 2 cells per 256-thr block (half-block per cell).
// All q/HKV/ctx traffic as short8 (16 B).
// ---------------------------------------------------------------------------
__global__ __launch_bounds__(256) void attn_v_kernel(
    const bf16* __restrict__ q, bf16* __restrict__ ctx,
    const bf16* __restrict__ HKV, const int* __restrict__ map,
    float* __restrict__ wout)
{
    const int h = threadIdx.x >> 7;           // half-block 0/1
    const int t = threadIdx.x & 127;          // lane within half
    const int cell = blockIdx.x * 2 + h;
    __shared__ float qs[2][DIM];
    __shared__ float sc[2][64];
    __shared__ float at[2][64];
    __shared__ int   ids[2][MAXH];
    __shared__ float msk[2][MAXH];

    if (t < MAXH) {
        int id = map[cell * MAXH + t];
        msk[h][t] = (id >= 0) ? 1.f : 0.f;
        ids[h][t] = (id >= 0) ? id : 0;
    }
    if (t < 96) {  // stage q: 96 x short8
        short8 qv = *reinterpret_cast<const short8*>((const short*)q + (size_t)cell * DIM + t * 8);
#pragma unroll
        for (int e = 0; e < 8; ++e) qs[h][t * 8 + e] = b2f(qv[e]);
    }
    __syncthreads();

    if (t < 64) {  // scores: head a = t>>3, slot j = t&7
        const int a = t >> 3, j = t & 7;
        const short* kp = (const short*)HKV + (size_t)ids[h][j] * 1536 + a * DHEAD;
        float s = 0.f;
#pragma unroll
        for (int c = 0; c < 12; ++c) {
            short8 kv = *reinterpret_cast<const short8*>(kp + c * 8);
#pragma unroll
            for (int e = 0; e < 8; ++e)
                s += qs[h][a * DHEAD + c * 8 + e] * b2f(kv[e]);
        }
        s *= 0.10206207261596577f;  // 1/sqrt(96)
        sc[h][t] = (msk[h][j] != 0.f) ? s : -1e9f;
    }
    __syncthreads();

    if (t < NHEADS) {  // softmax per head
        float m = -3e38f;
        for (int j = 0; j < MAXH; ++j) m = fmaxf(m, sc[h][t * 8 + j]);
        float e[MAXH]; float sum = 0.f;
        for (int j = 0; j < MAXH; ++j) { e[j] = expf(sc[h][t * 8 + j] - m); sum += e[j]; }
        const float inv = 1.f / sum;
        for (int j = 0; j < MAXH; ++j)
            at[h][t * 8 + j] = (msk[h][j] != 0.f) ? e[j] * inv : 0.f;
    }
    __syncthreads();

    if (t < MAXH) {  // head-averaged weights
        float s = 0.f;
        for (int a = 0; a < NHEADS; ++a) s += at[h][a * 8 + t];
        wout[(size_t)cell * MAXH + t] = s * 0.125f;
    }

    if (t < 96) {  // ctx: dims [t*8, t*8+8), head a = t/12
        const int a = t / 12, d0 = t * 8;
        float acc[8];
#pragma unroll
        for (int e = 0; e < 8; ++e) acc[e] = 0.f;
#pragma unroll
        for (int j = 0; j < MAXH; ++j) {
            short8 vv = *reinterpret_cast<const short8*>(
                (const short*)HKV + (size_t)ids[h][j] * 1536 + DIM + d0);
            const float w = at[h][a * 8 + j];
#pragma unroll
            for (int e = 0; e < 8; ++e) acc[e] += w * b2f(vv[e]);
        }
        short8 o;
#pragma unroll
        for (int e = 0; e < 8; ++e) o[e] = f2b(acc[e]);
        *reinterpret_cast<short8*>((short*)ctx + (size_t)cell * DIM + d0) = o;
    }
}

// ---------------------------------------------------------------------------
// LayerNorm + ReLU + has-select, IN-PLACE, vectorized; 2 cells per 384-thr
// block (three waves per cell; halves are wave-aligned: 192 = 3 x 64).
// ---------------------------------------------------------------------------
__global__ __launch_bounds__(384) void ln_v_kernel(
    float* io, const int* __restrict__ map,
    const float* __restrict__ ce, const int* __restrict__ pos,
    const float* __restrict__ re, const float* __restrict__ co,
    const float* __restrict__ g, const float* __restrict__ b)
{
    const int h = threadIdx.x / 192;          // half 0/1
    const int t = threadIdx.x % 192;
    const int cell = blockIdx.x * 2 + h;
    const int wave = t >> 6, lane = t & 63;
    __shared__ float ws_[2][3], wq_[2][3];
    __shared__ int hasf[2];
    if (threadIdx.x < 2) hasf[threadIdx.x] = 0;

    float* hp = io + (size_t)cell * DIM;
    floatx4 v = *reinterpret_cast<const floatx4*>(hp + t * 4);
    float s  = v[0] + v[1] + v[2] + v[3];
    float q2 = v[0]*v[0] + v[1]*v[1] + v[2]*v[2] + v[3]*v[3];
#pragma unroll
    for (int off = 32; off > 0; off >>= 1) {
        s  += __shfl_down(s, off);
        q2 += __shfl_down(q2, off);
    }
    __syncthreads();           // hasf init visible
    if (t < MAXH && map[cell * MAXH + t] >= 0) hasf[h] = 1;
    if (lane == 0) { ws_[h][wave] = s; wq_[h][wave] = q2; }
    __syncthreads();

    const float mu  = (ws_[h][0] + ws_[h][1] + ws_[h][2]) * (1.f / 768.f);
    const float var = (wq_[h][0] + wq_[h][1] + wq_[h][2]) * (1.f / 768.f) - mu * mu;
    const float inv = rsqrtf(var + 1e-5f);

    if (hasf[h]) {
        floatx4 gv = *reinterpret_cast<const floatx4*>(g + t * 4);
        floatx4 bv = *reinterpret_cast<const floatx4*>(b + t * 4);
        floatx4 o;
#pragma unroll
        for (int e = 0; e < 4; ++e)
            o[e] = fmaxf((v[e] - mu) * inv * gv[e] + bv[e], 0.f);
        *reinterpret_cast<floatx4*>(hp + t * 4) = o;
    } else {
        int pr = pos[cell * 2 + 0]; pr = min(max(pr, 0), 99);
        int pc = pos[cell * 2 + 1]; pc = min(max(pc, 0), 99);
        floatx4 a0 = *reinterpret_cast<const floatx4*>(ce + (size_t)cell * DIM + t * 4);
        floatx4 b0 = *reinterpret_cast<const floatx4*>(re + (size_t)pr * DIM + t * 4);
        floatx4 c0 = *reinterpret_cast<const floatx4*>(co + (size_t)pc * DIM + t * 4);
        floatx4 o;
#pragma unroll
        for (int e = 0; e < 4; ++e) o[e] = a0[e] + b0[e] + c0[e];
        *reinterpret_cast<floatx4*>(hp + t * 4) = o;
    }
}

// ---------------------------------------------------------------------------
extern "C" void kernel_launch(void* const* d_in, const int* in_sizes, int n_in,
                              void* d_out, int out_size, void* d_ws, size_t ws_size,
                              hipStream_t stream) {
    (void)in_sizes; (void)n_in; (void)out_size; (void)ws_size;

    const float* cell_emb  = (const float*)d_in[0];
    const float* hdr_emb   = (const float*)d_in[1];
    const int*   map       = (const int*)d_in[2];
    const int*   pos       = (const int*)d_in[3];
    const float* in_proj_w = (const float*)d_in[4];   // [2304, 768]
    const float* in_proj_b = (const float*)d_in[5];
    const float* out_w     = (const float*)d_in[6];   // [768, 768]
    const float* out_b     = (const float*)d_in[7];
    const float* row_emb   = (const float*)d_in[8];
    const float* col_emb   = (const float*)d_in[9];
    const float* fus_w     = (const float*)d_in[10];  // [768, 1536]
    const float* fus_b     = (const float*)d_in[11];
    const float* ln_g      = (const float*)d_in[12];
    const float* ln_b      = (const float*)d_in[13];
    float* out = (float*)d_out;

    // ws layout (bytes) — total 56,623,104 (proven available: R6-R8 ran it):
    //   HKV   bf16 [512,1536]  @ 0          ( 1,572,864)
    //   att_b bf16 [16384,768] @ 1572864    (25,165,824)
    //   cwp_b bf16 [16384,768] @ 26738688   (25,165,824)
    //   Wq_b  bf16 [768,768]   @ 51904512   ( 1,179,648)
    //   Wo_b  bf16 [768,768]   @ 53084160   ( 1,179,648)
    //   Wf_b  bf16 [768,1536]  @ 54263808   ( 2,359,296)
    char* ws = (char*)d_ws;
    bf16* HKV    = (bf16*)ws;
    bf16* att_b  = (bf16*)(ws + 1572864);
    bf16* cwp_b  = (bf16*)(ws + 26738688);
    bf16* Wq_b   = (bf16*)(ws + 51904512);
    bf16* Wo_b   = (bf16*)(ws + 53084160);
    bf16* Wf_b   = (bf16*)(ws + 54263808);
    // d_out raw-byte scratch: q_b bf16 @ [0,25165824), ctx_b @ [25165824,50331648)
    bf16* q_b    = (bf16*)d_out;
    bf16* ctx_b  = (bf16*)((char*)d_out + 25165824);

    // 1. PREP: cwp_b + Wq_b/Wo_b/Wf_b converts + HKV GEMM (one dispatch)
    prep_kernel<<<8640, 256, 0, stream>>>(
        cell_emb, pos, row_emb, col_emb, cwp_b,
        in_proj_w, Wq_b, out_w, Wo_b, fus_w, Wf_b,
        hdr_emb, in_proj_b, HKV);

    // 2. q_b = cwp_b @ Wq_b^T + bq  (bf16 out -> d_out bytes [0,25MB))
    gemm_bf<0, 1><<<768, 256, 0, stream>>>(
        cwp_b, nullptr, Wq_b, DIM, in_proj_b, nullptr, q_b, DIM);

    // 3. attention: q_b -> ctx_b; weights -> d_out tail (fp32)
    attn_v_kernel<<<NCELLS / 2, 256, 0, stream>>>(q_b, ctx_b, HKV, map, out + ND);

    // 4. att_b = ctx_b @ Wo_b^T + out_b  (bf16 out -> ws)
    gemm_bf<0, 1><<<768, 256, 0, stream>>>(
        ctx_b, nullptr, Wo_b, DIM, out_b, nullptr, att_b, DIM);

    // 5. h = [cwp_b | att_b] @ Wf_b^T + fus_b  (fp32 out -> d_out; q/ctx dead)
    gemm_bf<1, 0><<<768, 256, 0, stream>>>(
        cwp_b, att_b, Wf_b, 1536, fus_b, out, nullptr, 1536);

    // 6. LayerNorm + ReLU + select (in-place on d_out fp32)
    ln_v_kernel<<<NCELLS / 2, 384, 0, stream>>>(out, map, cell_emb, pos,
                                                row_emb, col_emb, ln_g, ln_b);
}